// Round 1
// baseline (697.245 us; speedup 1.0000x reference)
//
#include <hip/hip_runtime.h>
#include <hip/hip_bf16.h>
#include <math.h>

#define DIM 512
#define HID 2048
#define NE  8

typedef __attribute__((ext_vector_type(8))) short short8;
typedef __attribute__((ext_vector_type(4))) float f32x4;
typedef unsigned short ushort_t;

static __device__ __forceinline__ ushort_t f2bf(float f) {
    unsigned int x = __builtin_bit_cast(unsigned int, f);
    unsigned int lsb = (x >> 16) & 1u;
    x += 0x7fffu + lsb;
    return (ushort_t)(x >> 16);
}

// ---------------- fp32 -> bf16 bulk convert ----------------
__global__ void k_cvt(const float* __restrict__ src, ushort_t* __restrict__ dst, int n) {
    int i = blockIdx.x * blockDim.x + threadIdx.x;
    int stride = gridDim.x * blockDim.x;
    int n4 = n >> 2;
    for (int j = i; j < n4; j += stride) {
        float4 v = ((const float4*)src)[j];
        ushort4 o;
        o.x = f2bf(v.x); o.y = f2bf(v.y); o.z = f2bf(v.z); o.w = f2bf(v.w);
        ((ushort4*)dst)[j] = o;
    }
}

// ---------------- router: logits (f64), softmax, top-2 ----------------
__global__ __launch_bounds__(256) void k_router(const float* __restrict__ x,
    const float* __restrict__ Wr, ushort_t* __restrict__ xb,
    float* __restrict__ probs, int* __restrict__ tidx, float* __restrict__ tw, int T)
{
    int lane = threadIdx.x & 63;
    int t = blockIdx.x * 4 + (threadIdx.x >> 6);
    if (t >= T) return;
    const float* xr = x + (size_t)t * DIM;
    double acc[NE];
#pragma unroll
    for (int e = 0; e < NE; e++) acc[e] = 0.0;
    for (int i = lane; i < DIM; i += 64) {
        float xv = xr[i];
        xb[(size_t)t * DIM + i] = f2bf(xv);
        double xd = (double)xv;
#pragma unroll
        for (int e = 0; e < NE; e++) acc[e] += xd * (double)Wr[e * DIM + i];
    }
#pragma unroll
    for (int e = 0; e < NE; e++) {
#pragma unroll
        for (int off = 32; off > 0; off >>= 1) acc[e] += __shfl_xor(acc[e], off);
    }
    double mx = acc[0];
#pragma unroll
    for (int e = 1; e < NE; e++) mx = fmax(mx, acc[e]);
    double p[NE], sum = 0.0;
#pragma unroll
    for (int e = 0; e < NE; e++) { p[e] = exp(acc[e] - mx); sum += p[e]; }
    float pr[NE];
#pragma unroll
    for (int e = 0; e < NE; e++) pr[e] = (float)(p[e] / sum);
    if (lane < NE) probs[(size_t)t * NE + lane] = pr[lane];
    if (lane == 0) {
        int i1 = 0; float b1v = pr[0];
#pragma unroll
        for (int e = 1; e < NE; e++) if (pr[e] > b1v) { b1v = pr[e]; i1 = e; }
        int i2 = -1; float b2v = -1.f;
#pragma unroll
        for (int e = 0; e < NE; e++) if (e != i1 && pr[e] > b2v) { b2v = pr[e]; i2 = e; }
        float s2 = b1v + b2v + 1e-8f;
        tidx[t * 2] = i1; tidx[t * 2 + 1] = i2;
        tw[t * 2] = b1v / s2; tw[t * 2 + 1] = b2v / s2;
    }
}

// ---------------- per-(slot,expert) histogram ----------------
__global__ void k_hist(const int* __restrict__ tidx, int* __restrict__ cnt, int T) {
    int t = blockIdx.x * blockDim.x + threadIdx.x;
    if (t >= T) return;
    atomicAdd(&cnt[tidx[t * 2]], 1);
    atomicAdd(&cnt[NE + tidx[t * 2 + 1]], 1);
}

// ---------------- capacity keep (exact rank) + renormalize ----------------
__global__ void k_keep(const int* __restrict__ tidx, const float* __restrict__ tw,
                       const int* __restrict__ cnt, float* __restrict__ tw2, int T, int cap)
{
    int t = blockIdx.x * blockDim.x + threadIdx.x;
    if (t >= T) return;
    float wk[2];
#pragma unroll
    for (int s = 0; s < 2; s++) {
        int e = tidx[t * 2 + s];
        float w = tw[t * 2 + s];
        wk[s] = w;
        if (cnt[s * NE + e] > cap) {           // rare: exact stable-sort rank
            int rank = 0;
            for (int t2 = 0; t2 < T; t2++) {
                if (tidx[t2 * 2 + s] == e) {
                    float w2 = tw[t2 * 2 + s];
                    if (w2 > w || (w2 == w && t2 < t)) rank++;
                }
            }
            if (rank >= cap) wk[s] = 0.f;
        }
    }
    float denom = fmaxf(wk[0] + wk[1], 1e-8f);
    tw2[t * 2]     = wk[0] / denom;
    tw2[t * 2 + 1] = wk[1] / denom;
}

// ---------------- build per-(slot,expert) token lists ----------------
__global__ void k_build(const int* __restrict__ tidx, const float* __restrict__ tw2,
                        int* __restrict__ lcnt, int* __restrict__ ltok, float* __restrict__ lw,
                        int T, int cap)
{
    int t = blockIdx.x * blockDim.x + threadIdx.x;
    if (t >= T) return;
#pragma unroll
    for (int s = 0; s < 2; s++) {
        float w = tw2[t * 2 + s];
        if (w != 0.f) {
            int e = tidx[t * 2 + s];
            int p = atomicAdd(&lcnt[s * NE + e], 1);
            if (p < cap) {
                int base = (s * NE + e) * cap;
                ltok[base + p] = t;
                lw[base + p] = w;
            }
        }
    }
}

// ---------------- 128-aligned prefix offsets into h buffer ----------------
__global__ void k_off(const int* __restrict__ lcnt, int* __restrict__ loff) {
    if (threadIdx.x == 0 && blockIdx.x == 0) {
        for (int s = 0; s < 2; s++) {
            int o = 0;
            loff[s * (NE + 1)] = 0;
            for (int e = 0; e < NE; e++) {
                o += ((lcnt[s * NE + e] + 127) >> 7) << 7;
                loff[s * (NE + 1) + e + 1] = o;
            }
        }
    }
}

// ---------------- fc1: h = gelu(X @ W1^T + b1), bf16 MFMA, 128x128 tile ----------------
__global__ __launch_bounds__(256) void k_fc1(
    const ushort_t* __restrict__ xb, const ushort_t* __restrict__ W1b,
    const float* __restrict__ b1, const int* __restrict__ lcnt,
    const int* __restrict__ loff, const int* __restrict__ ltok,
    ushort_t* __restrict__ hbuf, int s, int cap, int maxtiles)
{
    int e  = blockIdx.x / maxtiles;
    int mt = blockIdx.x % maxtiles;
    int cnt = lcnt[s * NE + e];
    if (cnt > cap) cnt = cap;
    int m0 = mt * 128;
    if (m0 >= cnt) return;
    int n0 = blockIdx.y * 128;
    const int* toks = ltok + (s * NE + e) * cap;
    int hrow0 = loff[s * (NE + 1) + e] + m0;
    const ushort_t* Bsrc = W1b + (size_t)e * HID * DIM;

    __shared__ char smem[32768];
    char* As = smem;
    char* Bs = smem + 16384;

    int tid = threadIdx.x;
    int wave = tid >> 6, lane = tid & 63;
    int wm = wave >> 1, wn = wave & 1;

    const ushort_t* aSrc[4]; const ushort_t* bSrc[4]; int sOff[4];
#pragma unroll
    for (int i = 0; i < 4; i++) {
        int c = tid + 256 * i;
        int row = c >> 3, cc = c & 7;
        int gr = m0 + row;
        int tok = toks[gr < cnt ? gr : (cnt - 1)];
        aSrc[i] = xb + (size_t)tok * DIM + cc * 8;
        bSrc[i] = Bsrc + (size_t)(n0 + row) * DIM + cc * 8;
        sOff[i] = row * 128 + (((cc ^ (row & 7))) << 4);
    }

    f32x4 acc[4][4];
#pragma unroll
    for (int a = 0; a < 4; a++)
#pragma unroll
        for (int b = 0; b < 4; b++) acc[a][b] = (f32x4){0.f, 0.f, 0.f, 0.f};

    int aRow = wm * 64 + (lane & 15);
    int bRow = wn * 64 + (lane & 15);
    int kq = lane >> 4;

    for (int kt = 0; kt < DIM / 64; kt++) {
        __syncthreads();
#pragma unroll
        for (int i = 0; i < 4; i++) {
            uint4 va = *(const uint4*)(aSrc[i] + kt * 64);
            *(uint4*)(As + sOff[i]) = va;
            uint4 vb = *(const uint4*)(bSrc[i] + kt * 64);
            *(uint4*)(Bs + sOff[i]) = vb;
        }
        __syncthreads();
#pragma unroll
        for (int kk = 0; kk < 2; kk++) {
            int c16 = kk * 4 + kq;
            short8 af[4], bfr[4];
#pragma unroll
            for (int mf = 0; mf < 4; mf++) {
                int rr = aRow + mf * 16;
                af[mf] = *(const short8*)(As + rr * 128 + ((c16 ^ (rr & 7)) << 4));
            }
#pragma unroll
            for (int nf = 0; nf < 4; nf++) {
                int rr = bRow + nf * 16;
                bfr[nf] = *(const short8*)(Bs + rr * 128 + ((c16 ^ (rr & 7)) << 4));
            }
#pragma unroll
            for (int mf = 0; mf < 4; mf++)
#pragma unroll
                for (int nf = 0; nf < 4; nf++)
                    acc[mf][nf] = __builtin_amdgcn_mfma_f32_16x16x32_bf16(af[mf], bfr[nf], acc[mf][nf], 0, 0, 0);
        }
    }

    const float* b1e = b1 + e * HID;
#pragma unroll
    for (int nf = 0; nf < 4; nf++) {
        int col = n0 + wn * 64 + nf * 16 + (lane & 15);
        float bias = b1e[col];
#pragma unroll
        for (int mf = 0; mf < 4; mf++) {
            int rbase = wm * 64 + mf * 16 + (lane >> 4) * 4;
#pragma unroll
            for (int r = 0; r < 4; r++) {
                int rl = rbase + r;
                float v = acc[mf][nf][r] + bias;
                float g = 0.5f * v * (1.f + erff(v * 0.70710678118654752f));
                ushort_t o = ((m0 + rl) < cnt) ? f2bf(g) : (ushort_t)0;
                hbuf[(size_t)(hrow0 + rl) * HID + col] = o;
            }
        }
    }
}

// ---------------- fc2: out[tok] (=/+=) w * (H @ W2^T + b2) ----------------
__global__ __launch_bounds__(256) void k_fc2(
    const ushort_t* __restrict__ hbuf, const ushort_t* __restrict__ W2b,
    const float* __restrict__ b2, const int* __restrict__ lcnt,
    const int* __restrict__ loff, const int* __restrict__ ltok,
    const float* __restrict__ lw, float* __restrict__ out, int s, int cap, int maxtiles)
{
    int e  = blockIdx.x / maxtiles;
    int mt = blockIdx.x % maxtiles;
    int cnt = lcnt[s * NE + e];
    if (cnt > cap) cnt = cap;
    int m0 = mt * 128;
    if (m0 >= cnt) return;
    int n0 = blockIdx.y * 128;
    const int* toks = ltok + (s * NE + e) * cap;
    const float* lww = lw + (s * NE + e) * cap;
    int hrow0 = loff[s * (NE + 1) + e] + m0;
    const ushort_t* Bsrc = W2b + (size_t)e * DIM * HID;

    __shared__ char smem[32768];
    char* As = smem;
    char* Bs = smem + 16384;

    int tid = threadIdx.x;
    int wave = tid >> 6, lane = tid & 63;
    int wm = wave >> 1, wn = wave & 1;

    const ushort_t* aSrc[4]; const ushort_t* bSrc[4]; int sOff[4];
#pragma unroll
    for (int i = 0; i < 4; i++) {
        int c = tid + 256 * i;
        int row = c >> 3, cc = c & 7;
        aSrc[i] = hbuf + (size_t)(hrow0 + row) * HID + cc * 8;
        bSrc[i] = Bsrc + (size_t)(n0 + row) * HID + cc * 8;
        sOff[i] = row * 128 + (((cc ^ (row & 7))) << 4);
    }

    f32x4 acc[4][4];
#pragma unroll
    for (int a = 0; a < 4; a++)
#pragma unroll
        for (int b = 0; b < 4; b++) acc[a][b] = (f32x4){0.f, 0.f, 0.f, 0.f};

    int aRow = wm * 64 + (lane & 15);
    int bRow = wn * 64 + (lane & 15);
    int kq = lane >> 4;

    for (int kt = 0; kt < HID / 64; kt++) {
        __syncthreads();
#pragma unroll
        for (int i = 0; i < 4; i++) {
            uint4 va = *(const uint4*)(aSrc[i] + kt * 64);
            *(uint4*)(As + sOff[i]) = va;
            uint4 vb = *(const uint4*)(bSrc[i] + kt * 64);
            *(uint4*)(Bs + sOff[i]) = vb;
        }
        __syncthreads();
#pragma unroll
        for (int kk = 0; kk < 2; kk++) {
            int c16 = kk * 4 + kq;
            short8 af[4], bfr[4];
#pragma unroll
            for (int mf = 0; mf < 4; mf++) {
                int rr = aRow + mf * 16;
                af[mf] = *(const short8*)(As + rr * 128 + ((c16 ^ (rr & 7)) << 4));
            }
#pragma unroll
            for (int nf = 0; nf < 4; nf++) {
                int rr = bRow + nf * 16;
                bfr[nf] = *(const short8*)(Bs + rr * 128 + ((c16 ^ (rr & 7)) << 4));
            }
#pragma unroll
            for (int mf = 0; mf < 4; mf++)
#pragma unroll
                for (int nf = 0; nf < 4; nf++)
                    acc[mf][nf] = __builtin_amdgcn_mfma_f32_16x16x32_bf16(af[mf], bfr[nf], acc[mf][nf], 0, 0, 0);
        }
    }

    const float* b2e = b2 + e * DIM;
#pragma unroll
    for (int nf = 0; nf < 4; nf++) {
        int col = n0 + wn * 64 + nf * 16 + (lane & 15);
        float bias = b2e[col];
#pragma unroll
        for (int mf = 0; mf < 4; mf++) {
            int rbase = wm * 64 + mf * 16 + (lane >> 4) * 4;
#pragma unroll
            for (int r = 0; r < 4; r++) {
                int rl = rbase + r;
                int gr = m0 + rl;
                if (gr < cnt) {
                    int tok = toks[gr];
                    float w = lww[gr];
                    float v = (acc[mf][nf][r] + bias) * w;
                    float* p = out + (size_t)tok * DIM + col;
                    if (s == 0) *p = v;
                    else        *p = *p + v;
                }
            }
        }
    }
}

// ---------------- aux loss (deterministic single-block reduce) ----------------
__global__ __launch_bounds__(256) void k_aux(const float* __restrict__ probs,
    const float* __restrict__ tw2, const int* __restrict__ tidx,
    float* __restrict__ outaux, int T)
{
    __shared__ float red[256 * 16];
    float imp[NE], ld[NE];
#pragma unroll
    for (int e = 0; e < NE; e++) { imp[e] = 0.f; ld[e] = 0.f; }
    for (int t = threadIdx.x; t < T; t += 256) {
#pragma unroll
        for (int e = 0; e < NE; e++) imp[e] += probs[(size_t)t * NE + e];
#pragma unroll
        for (int s = 0; s < 2; s++) ld[tidx[t * 2 + s]] += tw2[t * 2 + s];
    }
#pragma unroll
    for (int e = 0; e < NE; e++) {
        red[threadIdx.x * 16 + e] = imp[e];
        red[threadIdx.x * 16 + 8 + e] = ld[e];
    }
    __syncthreads();
    for (int off = 128; off > 0; off >>= 1) {
        if (threadIdx.x < off) {
#pragma unroll
            for (int j = 0; j < 16; j++)
                red[threadIdx.x * 16 + j] += red[(threadIdx.x + off) * 16 + j];
        }
        __syncthreads();
    }
    if (threadIdx.x == 0) {
        float invT = 1.f / (float)T;
        float aux = 0.f;
        for (int e = 0; e < NE; e++)
            aux += (red[e] * invT) * (red[8 + e] * invT) * (float)NE;
        outaux[0] = aux;
    }
}

// ---------------- launch ----------------
extern "C" void kernel_launch(void* const* d_in, const int* in_sizes, int n_in,
                              void* d_out, int out_size, void* d_ws, size_t ws_size,
                              hipStream_t stream)
{
    const float* x  = (const float*)d_in[0];
    const float* Wr = (const float*)d_in[1];
    const float* W1 = (const float*)d_in[2];
    const float* b1 = (const float*)d_in[3];
    const float* W2 = (const float*)d_in[4];
    const float* b2 = (const float*)d_in[5];
    float* out = (float*)d_out;

    int T = in_sizes[0] / DIM;
    int cap = (int)(1.25 * (double)T * 2.0 / 8.0);
    if (cap < 1) cap = 1;
    int maxtiles = (cap + 127) / 128;

    char* w = (char*)d_ws;
    size_t off = 0;
    auto alloc = [&](size_t bytes) {
        char* p = w + off;
        off = (off + bytes + 255) & ~(size_t)255;
        return p;
    };
    ushort_t* xb   = (ushort_t*)alloc((size_t)T * DIM * 2);
    ushort_t* W1b  = (ushort_t*)alloc((size_t)NE * HID * DIM * 2);
    ushort_t* W2b  = (ushort_t*)alloc((size_t)NE * DIM * HID * 2);
    ushort_t* hbuf = (ushort_t*)alloc(((size_t)T + 1024) * HID * 2);
    float* probs   = (float*)alloc((size_t)T * NE * 4);
    int*   tidx    = (int*)alloc((size_t)T * 2 * 4);
    float* tw      = (float*)alloc((size_t)T * 2 * 4);
    float* tw2     = (float*)alloc((size_t)T * 2 * 4);
    int*   cnt     = (int*)alloc(64);
    int*   lcnt    = (int*)alloc(64);
    int*   loff    = (int*)alloc(128);
    int*   ltok    = (int*)alloc((size_t)2 * NE * cap * 4);
    float* lwb     = (float*)alloc((size_t)2 * NE * cap * 4);

    hipMemsetAsync(d_out, 0, (size_t)out_size * 4, stream);
    hipMemsetAsync(cnt, 0, 64, stream);
    hipMemsetAsync(lcnt, 0, 64, stream);

    k_cvt<<<2048, 256, 0, stream>>>(W1, W1b, NE * HID * DIM);
    k_cvt<<<2048, 256, 0, stream>>>(W2, W2b, NE * DIM * HID);
    k_router<<<(T + 3) / 4, 256, 0, stream>>>(x, Wr, xb, probs, tidx, tw, T);
    k_hist<<<(T + 255) / 256, 256, 0, stream>>>(tidx, cnt, T);
    k_keep<<<(T + 255) / 256, 256, 0, stream>>>(tidx, tw, cnt, tw2, T, cap);
    k_build<<<(T + 255) / 256, 256, 0, stream>>>(tidx, tw2, lcnt, ltok, lwb, T, cap);
    k_off<<<1, 64, 0, stream>>>(lcnt, loff);
    for (int s = 0; s < 2; s++) {
        k_fc1<<<dim3(NE * maxtiles, HID / 128), 256, 0, stream>>>(
            xb, W1b, b1, lcnt, loff, ltok, hbuf, s, cap, maxtiles);
        k_fc2<<<dim3(NE * maxtiles, DIM / 128), 256, 0, stream>>>(
            hbuf, W2b, b2, lcnt, loff, ltok, lwb, out, s, cap, maxtiles);
    }
    k_aux<<<1, 256, 0, stream>>>(probs, tw2, tidx, out + (size_t)T * DIM, T);
}

// Round 3
// 523.906 us; speedup vs baseline: 1.3309x; 1.3309x over previous
//
#include <hip/hip_runtime.h>
#include <hip/hip_bf16.h>
#include <math.h>

#define DIM 512
#define HID 2048
#define NE  8
#define CSTRIDE 32   // counter padding: 128B apart to kill cacheline ping-pong

typedef __attribute__((ext_vector_type(8))) short short8;
typedef __attribute__((ext_vector_type(4))) float f32x4;
typedef unsigned short ushort_t;

static __device__ __forceinline__ ushort_t f2bf(float f) {
    unsigned int x = __builtin_bit_cast(unsigned int, f);
    unsigned int lsb = (x >> 16) & 1u;
    x += 0x7fffu + lsb;
    return (ushort_t)(x >> 16);
}

// async global->LDS, 16B per lane. LDS dest is wave-uniform base + lane*16.
static __device__ __forceinline__ void gld16(const void* g, void* l) {
    __builtin_amdgcn_global_load_lds(
        (const __attribute__((address_space(1))) void*)g,
        (__attribute__((address_space(3))) void*)l,
        16, 0, 0);
}

// ---------------- fp32 -> bf16 bulk convert ----------------
__global__ void k_cvt(const float* __restrict__ src, ushort_t* __restrict__ dst, int n) {
    int i = blockIdx.x * blockDim.x + threadIdx.x;
    int stride = gridDim.x * blockDim.x;
    int n4 = n >> 2;
    for (int j = i; j < n4; j += stride) {
        float4 v = ((const float4*)src)[j];
        ushort4 o;
        o.x = f2bf(v.x); o.y = f2bf(v.y); o.z = f2bf(v.z); o.w = f2bf(v.w);
        ((ushort4*)dst)[j] = o;
    }
}

// ---------------- router: logits (f64), softmax, top-2 ----------------
__global__ __launch_bounds__(256) void k_router(const float* __restrict__ x,
    const float* __restrict__ Wr, ushort_t* __restrict__ xb,
    float* __restrict__ probs, int* __restrict__ tidx, float* __restrict__ tw, int T)
{
    int lane = threadIdx.x & 63;
    int t = blockIdx.x * 4 + (threadIdx.x >> 6);
    if (t >= T) return;
    const float* xr = x + (size_t)t * DIM;
    double acc[NE];
#pragma unroll
    for (int e = 0; e < NE; e++) acc[e] = 0.0;
    for (int i = lane; i < DIM; i += 64) {
        float xv = xr[i];
        xb[(size_t)t * DIM + i] = f2bf(xv);
        double xd = (double)xv;
#pragma unroll
        for (int e = 0; e < NE; e++) acc[e] += xd * (double)Wr[e * DIM + i];
    }
#pragma unroll
    for (int e = 0; e < NE; e++) {
#pragma unroll
        for (int off = 32; off > 0; off >>= 1) acc[e] += __shfl_xor(acc[e], off);
    }
    double mx = acc[0];
#pragma unroll
    for (int e = 1; e < NE; e++) mx = fmax(mx, acc[e]);
    double p[NE], sum = 0.0;
#pragma unroll
    for (int e = 0; e < NE; e++) { p[e] = exp(acc[e] - mx); sum += p[e]; }
    float pr[NE];
#pragma unroll
    for (int e = 0; e < NE; e++) pr[e] = (float)(p[e] / sum);
    if (lane < NE) probs[(size_t)t * NE + lane] = pr[lane];
    if (lane == 0) {
        int i1 = 0; float b1v = pr[0];
#pragma unroll
        for (int e = 1; e < NE; e++) if (pr[e] > b1v) { b1v = pr[e]; i1 = e; }
        int i2 = -1; float b2v = -1.f;
#pragma unroll
        for (int e = 0; e < NE; e++) if (e != i1 && pr[e] > b2v) { b2v = pr[e]; i2 = e; }
        float s2 = b1v + b2v + 1e-8f;
        tidx[t * 2] = i1; tidx[t * 2 + 1] = i2;
        tw[t * 2] = b1v / s2; tw[t * 2 + 1] = b2v / s2;
    }
}

// ---------------- per-(slot,expert) histogram: block-aggregated ----------------
__global__ __launch_bounds__(256) void k_hist(const int* __restrict__ tidx,
                                              int* __restrict__ cnt, int T) {
    __shared__ int h[16];
    if (threadIdx.x < 16) h[threadIdx.x] = 0;
    __syncthreads();
    int stride = gridDim.x * blockDim.x;
    for (int t = blockIdx.x * blockDim.x + threadIdx.x; t < T; t += stride) {
        atomicAdd(&h[tidx[t * 2]], 1);
        atomicAdd(&h[8 + tidx[t * 2 + 1]], 1);
    }
    __syncthreads();
    if (threadIdx.x < 16 && h[threadIdx.x] != 0)
        atomicAdd(&cnt[threadIdx.x * CSTRIDE], h[threadIdx.x]);
}

// ---------------- capacity keep (exact rank) + renormalize ----------------
__global__ void k_keep(const int* __restrict__ tidx, const float* __restrict__ tw,
                       const int* __restrict__ cnt, float* __restrict__ tw2, int T, int cap)
{
    int t = blockIdx.x * blockDim.x + threadIdx.x;
    if (t >= T) return;
    float wk[2];
#pragma unroll
    for (int s = 0; s < 2; s++) {
        int e = tidx[t * 2 + s];
        float w = tw[t * 2 + s];
        wk[s] = w;
        if (cnt[(s * NE + e) * CSTRIDE] > cap) {   // rare: exact stable-sort rank
            int rank = 0;
            for (int t2 = 0; t2 < T; t2++) {
                if (tidx[t2 * 2 + s] == e) {
                    float w2 = tw[t2 * 2 + s];
                    if (w2 > w || (w2 == w && t2 < t)) rank++;
                }
            }
            if (rank >= cap) wk[s] = 0.f;
        }
    }
    float denom = fmaxf(wk[0] + wk[1], 1e-8f);
    tw2[t * 2]     = wk[0] / denom;
    tw2[t * 2 + 1] = wk[1] / denom;
}

// ---------------- build per-(slot,expert) token lists: block-aggregated ----------------
__global__ __launch_bounds__(256) void k_build(const int* __restrict__ tidx,
        const float* __restrict__ tw2, int* __restrict__ lcnt,
        int* __restrict__ ltok, float* __restrict__ lw, int T, int cap)
{
    __shared__ int h[16];
    __shared__ int base[16];
    if (threadIdx.x < 16) h[threadIdx.x] = 0;
    __syncthreads();
    int t = blockIdx.x * blockDim.x + threadIdx.x;
    int myslot[2] = {-1, -1};
    int mypos[2]  = {0, 0};
    if (t < T) {
#pragma unroll
        for (int s = 0; s < 2; s++) {
            float w = tw2[t * 2 + s];
            if (w != 0.f) {
                int se = s * NE + tidx[t * 2 + s];
                myslot[s] = se;
                mypos[s] = atomicAdd(&h[se], 1);   // LDS atomic: fast
            }
        }
    }
    __syncthreads();
    if (threadIdx.x < 16)
        base[threadIdx.x] = (h[threadIdx.x] != 0)
            ? atomicAdd(&lcnt[threadIdx.x * CSTRIDE], h[threadIdx.x]) : 0;
    __syncthreads();
#pragma unroll
    for (int s = 0; s < 2; s++) {
        if (myslot[s] >= 0) {
            int p = base[myslot[s]] + mypos[s];
            if (p < cap) {
                int b = myslot[s] * cap;
                ltok[b + p] = t;
                lw[b + p] = tw2[t * 2 + s];
            }
        }
    }
}

// ---------------- 128-aligned prefix offsets into h buffer ----------------
__global__ void k_off(const int* __restrict__ lcnt, int* __restrict__ loff) {
    if (threadIdx.x == 0 && blockIdx.x == 0) {
        for (int s = 0; s < 2; s++) {
            int o = 0;
            loff[s * (NE + 1)] = 0;
            for (int e = 0; e < NE; e++) {
                o += ((lcnt[(s * NE + e) * CSTRIDE] + 127) >> 7) << 7;
                loff[s * (NE + 1) + e + 1] = o;
            }
        }
    }
}

// ---------------- fc1: h = gelu(X @ W1^T + b1), bf16 MFMA, 128x128 tile ----------------
// Staging: global_load_lds width=16, linear LDS dest, pre-swizzled global source
// column (scc = cc ^ (row&7)); reads use the matching XOR so fragments land right.
__global__ __launch_bounds__(256) void k_fc1(
    const ushort_t* __restrict__ xb, const ushort_t* __restrict__ W1b,
    const float* __restrict__ b1, const int* __restrict__ lcnt,
    const int* __restrict__ loff, const int* __restrict__ ltok,
    ushort_t* __restrict__ hbuf, int s, int cap, int maxtiles)
{
    int e  = blockIdx.x / maxtiles;
    int mt = blockIdx.x % maxtiles;
    int cnt = lcnt[(s * NE + e) * CSTRIDE];
    if (cnt > cap) cnt = cap;
    int m0 = mt * 128;
    if (m0 >= cnt) return;
    int n0 = blockIdx.y * 128;
    const int* toks = ltok + (s * NE + e) * cap;
    int hrow0 = loff[s * (NE + 1) + e] + m0;
    const ushort_t* Bsrc = W1b + (size_t)e * HID * DIM;

    __shared__ char smem[32768];
    char* As = smem;
    char* Bs = smem + 16384;

    int tid = threadIdx.x;
    int wave = tid >> 6, lane = tid & 63;
    int wm = wave >> 1, wn = wave & 1;

    const char* aSrc[4]; const char* bSrc[4]; int ldst[4];
#pragma unroll
    for (int i = 0; i < 4; i++) {
        int c = tid + 256 * i;             // chunk id 0..1023
        int row = c >> 3, cc = c & 7;
        int scc = cc ^ (row & 7);          // pre-swizzled source column chunk
        int gr = m0 + row;
        int tok = toks[gr < cnt ? gr : (cnt - 1)];
        aSrc[i] = (const char*)(xb + (size_t)tok * DIM + scc * 8);
        bSrc[i] = (const char*)(Bsrc + (size_t)(n0 + row) * DIM + scc * 8);
        ldst[i] = (i * 256 + wave * 64) * 16;   // wave-uniform LDS base
    }

    f32x4 acc[4][4];
#pragma unroll
    for (int a = 0; a < 4; a++)
#pragma unroll
        for (int b = 0; b < 4; b++) acc[a][b] = (f32x4){0.f, 0.f, 0.f, 0.f};

    int aRow = wm * 64 + (lane & 15);
    int bRow = wn * 64 + (lane & 15);
    int kq = lane >> 4;

    for (int kt = 0; kt < DIM / 64; kt++) {
        __syncthreads();
#pragma unroll
        for (int i = 0; i < 4; i++) {
            gld16(aSrc[i] + kt * 128, As + ldst[i]);
            gld16(bSrc[i] + kt * 128, Bs + ldst[i]);
        }
        __syncthreads();
#pragma unroll
        for (int kk = 0; kk < 2; kk++) {
            int c16 = kk * 4 + kq;
            short8 af[4], bfr[4];
#pragma unroll
            for (int mf = 0; mf < 4; mf++) {
                int rr = aRow + mf * 16;
                af[mf] = *(const short8*)(As + rr * 128 + ((c16 ^ (rr & 7)) << 4));
            }
#pragma unroll
            for (int nf = 0; nf < 4; nf++) {
                int rr = bRow + nf * 16;
                bfr[nf] = *(const short8*)(Bs + rr * 128 + ((c16 ^ (rr & 7)) << 4));
            }
#pragma unroll
            for (int mf = 0; mf < 4; mf++)
#pragma unroll
                for (int nf = 0; nf < 4; nf++)
                    acc[mf][nf] = __builtin_amdgcn_mfma_f32_16x16x32_bf16(af[mf], bfr[nf], acc[mf][nf], 0, 0, 0);
        }
    }

    const float* b1e = b1 + e * HID;
#pragma unroll
    for (int nf = 0; nf < 4; nf++) {
        int col = n0 + wn * 64 + nf * 16 + (lane & 15);
        float bias = b1e[col];
#pragma unroll
        for (int mf = 0; mf < 4; mf++) {
            int rbase = wm * 64 + mf * 16 + (lane >> 4) * 4;
#pragma unroll
            for (int r = 0; r < 4; r++) {
                int rl = rbase + r;
                float v = acc[mf][nf][r] + bias;
                float g = 0.5f * v * (1.f + erff(v * 0.70710678118654752f));
                ushort_t o = ((m0 + rl) < cnt) ? f2bf(g) : (ushort_t)0;
                hbuf[(size_t)(hrow0 + rl) * HID + col] = o;
            }
        }
    }
}

// ---------------- fc2: out[tok] (=/+=) w * (H @ W2^T + b2) ----------------
__global__ __launch_bounds__(256) void k_fc2(
    const ushort_t* __restrict__ hbuf, const ushort_t* __restrict__ W2b,
    const float* __restrict__ b2, const int* __restrict__ lcnt,
    const int* __restrict__ loff, const int* __restrict__ ltok,
    const float* __restrict__ lw, float* __restrict__ out, int s, int cap, int maxtiles)
{
    int e  = blockIdx.x / maxtiles;
    int mt = blockIdx.x % maxtiles;
    int cnt = lcnt[(s * NE + e) * CSTRIDE];
    if (cnt > cap) cnt = cap;
    int m0 = mt * 128;
    if (m0 >= cnt) return;
    int n0 = blockIdx.y * 128;
    const int* toks = ltok + (s * NE + e) * cap;
    const float* lww = lw + (s * NE + e) * cap;
    int hrow0 = loff[s * (NE + 1) + e] + m0;
    const ushort_t* Bsrc = W2b + (size_t)e * DIM * HID;

    __shared__ char smem[32768];
    char* As = smem;
    char* Bs = smem + 16384;

    int tid = threadIdx.x;
    int wave = tid >> 6, lane = tid & 63;
    int wm = wave >> 1, wn = wave & 1;

    const char* aSrc[4]; const char* bSrc[4]; int ldst[4];
#pragma unroll
    for (int i = 0; i < 4; i++) {
        int c = tid + 256 * i;
        int row = c >> 3, cc = c & 7;
        int scc = cc ^ (row & 7);
        aSrc[i] = (const char*)(hbuf + (size_t)(hrow0 + row) * HID + scc * 8);
        bSrc[i] = (const char*)(Bsrc + (size_t)(n0 + row) * HID + scc * 8);
        ldst[i] = (i * 256 + wave * 64) * 16;
    }

    f32x4 acc[4][4];
#pragma unroll
    for (int a = 0; a < 4; a++)
#pragma unroll
        for (int b = 0; b < 4; b++) acc[a][b] = (f32x4){0.f, 0.f, 0.f, 0.f};

    int aRow = wm * 64 + (lane & 15);
    int bRow = wn * 64 + (lane & 15);
    int kq = lane >> 4;

    for (int kt = 0; kt < HID / 64; kt++) {
        __syncthreads();
#pragma unroll
        for (int i = 0; i < 4; i++) {
            gld16(aSrc[i] + kt * 128, As + ldst[i]);
            gld16(bSrc[i] + kt * 128, Bs + ldst[i]);
        }
        __syncthreads();
#pragma unroll
        for (int kk = 0; kk < 2; kk++) {
            int c16 = kk * 4 + kq;
            short8 af[4], bfr[4];
#pragma unroll
            for (int mf = 0; mf < 4; mf++) {
                int rr = aRow + mf * 16;
                af[mf] = *(const short8*)(As + rr * 128 + ((c16 ^ (rr & 7)) << 4));
            }
#pragma unroll
            for (int nf = 0; nf < 4; nf++) {
                int rr = bRow + nf * 16;
                bfr[nf] = *(const short8*)(Bs + rr * 128 + ((c16 ^ (rr & 7)) << 4));
            }
#pragma unroll
            for (int mf = 0; mf < 4; mf++)
#pragma unroll
                for (int nf = 0; nf < 4; nf++)
                    acc[mf][nf] = __builtin_amdgcn_mfma_f32_16x16x32_bf16(af[mf], bfr[nf], acc[mf][nf], 0, 0, 0);
        }
    }

    const float* b2e = b2 + e * DIM;
#pragma unroll
    for (int nf = 0; nf < 4; nf++) {
        int col = n0 + wn * 64 + nf * 16 + (lane & 15);
        float bias = b2e[col];
#pragma unroll
        for (int mf = 0; mf < 4; mf++) {
            int rbase = wm * 64 + mf * 16 + (lane >> 4) * 4;
#pragma unroll
            for (int r = 0; r < 4; r++) {
                int rl = rbase + r;
                int gr = m0 + rl;
                if (gr < cnt) {
                    int tok = toks[gr];
                    float w = lww[gr];
                    float v = (acc[mf][nf][r] + bias) * w;
                    float* p = out + (size_t)tok * DIM + col;
                    if (s == 0) *p = v;
                    else        *p = *p + v;
                }
            }
        }
    }
}

// ---------------- aux loss: two-stage deterministic reduce ----------------
__global__ __launch_bounds__(256) void k_aux1(const float* __restrict__ probs,
    const float* __restrict__ tw2, const int* __restrict__ tidx,
    float* __restrict__ partial, int T)
{
    __shared__ float red[256 * 16];
    float imp[NE], ld[NE];
#pragma unroll
    for (int e = 0; e < NE; e++) { imp[e] = 0.f; ld[e] = 0.f; }
    int stride = gridDim.x * blockDim.x;
    for (int t = blockIdx.x * blockDim.x + threadIdx.x; t < T; t += stride) {
#pragma unroll
        for (int e = 0; e < NE; e++) imp[e] += probs[(size_t)t * NE + e];
#pragma unroll
        for (int s = 0; s < 2; s++) ld[tidx[t * 2 + s]] += tw2[t * 2 + s];
    }
#pragma unroll
    for (int e = 0; e < NE; e++) {
        red[threadIdx.x * 16 + e] = imp[e];
        red[threadIdx.x * 16 + 8 + e] = ld[e];
    }
    __syncthreads();
    for (int off = 128; off > 0; off >>= 1) {
        if (threadIdx.x < off) {
#pragma unroll
            for (int j = 0; j < 16; j++)
                red[threadIdx.x * 16 + j] += red[(threadIdx.x + off) * 16 + j];
        }
        __syncthreads();
    }
    if (threadIdx.x < 16) partial[blockIdx.x * 16 + threadIdx.x] = red[threadIdx.x];
}

__global__ void k_aux2(const float* __restrict__ partial, float* __restrict__ outaux,
                       int nb, int T)
{
    __shared__ float s[16];
    if (threadIdx.x < 16) {
        float a = 0.f;
        for (int b = 0; b < nb; b++) a += partial[b * 16 + threadIdx.x];
        s[threadIdx.x] = a;
    }
    __syncthreads();
    if (threadIdx.x == 0) {
        float invT = 1.f / (float)T;
        float aux = 0.f;
        for (int e = 0; e < NE; e++)
            aux += (s[e] * invT) * (s[8 + e] * invT) * (float)NE;
        outaux[0] = aux;
    }
}

// ---------------- launch ----------------
extern "C" void kernel_launch(void* const* d_in, const int* in_sizes, int n_in,
                              void* d_out, int out_size, void* d_ws, size_t ws_size,
                              hipStream_t stream)
{
    const float* x  = (const float*)d_in[0];
    const float* Wr = (const float*)d_in[1];
    const float* W1 = (const float*)d_in[2];
    const float* b1 = (const float*)d_in[3];
    const float* W2 = (const float*)d_in[4];
    const float* b2 = (const float*)d_in[5];
    float* out = (float*)d_out;

    int T = in_sizes[0] / DIM;
    int cap = (int)(1.25 * (double)T * 2.0 / 8.0);
    if (cap < 1) cap = 1;
    int maxtiles = (cap + 127) / 128;

    char* w = (char*)d_ws;
    size_t off = 0;
    auto alloc = [&](size_t bytes) {
        char* p = w + off;
        off = (off + bytes + 255) & ~(size_t)255;
        return p;
    };
    ushort_t* xb   = (ushort_t*)alloc((size_t)T * DIM * 2);
    ushort_t* W1b  = (ushort_t*)alloc((size_t)NE * HID * DIM * 2);
    ushort_t* W2b  = (ushort_t*)alloc((size_t)NE * DIM * HID * 2);
    ushort_t* hbuf = (ushort_t*)alloc(((size_t)T + 1024) * HID * 2);
    float* probs   = (float*)alloc((size_t)T * NE * 4);
    int*   tidx    = (int*)alloc((size_t)T * 2 * 4);
    float* tw      = (float*)alloc((size_t)T * 2 * 4);
    float* tw2     = (float*)alloc((size_t)T * 2 * 4);
    int*   cnt     = (int*)alloc(16 * CSTRIDE * 4);
    int*   lcnt    = (int*)alloc(16 * CSTRIDE * 4);
    int*   loff    = (int*)alloc(128);
    int*   ltok    = (int*)alloc((size_t)2 * NE * cap * 4);
    float* lwb     = (float*)alloc((size_t)2 * NE * cap * 4);
    float* partial = (float*)alloc(64 * 16 * 4);

    (void)hipMemsetAsync(d_out, 0, (size_t)out_size * 4, stream);
    (void)hipMemsetAsync(cnt, 0, 16 * CSTRIDE * 4, stream);
    (void)hipMemsetAsync(lcnt, 0, 16 * CSTRIDE * 4, stream);

    k_cvt<<<2048, 256, 0, stream>>>(W1, W1b, NE * HID * DIM);
    k_cvt<<<2048, 256, 0, stream>>>(W2, W2b, NE * DIM * HID);
    k_router<<<(T + 3) / 4, 256, 0, stream>>>(x, Wr, xb, probs, tidx, tw, T);
    k_hist<<<64, 256, 0, stream>>>(tidx, cnt, T);
    k_keep<<<(T + 255) / 256, 256, 0, stream>>>(tidx, tw, cnt, tw2, T, cap);
    k_build<<<(T + 255) / 256, 256, 0, stream>>>(tidx, tw2, lcnt, ltok, lwb, T, cap);
    k_off<<<1, 64, 0, stream>>>(lcnt, loff);
    for (int s = 0; s < 2; s++) {
        k_fc1<<<dim3(NE * maxtiles, HID / 128), 256, 0, stream>>>(
            xb, W1b, b1, lcnt, loff, ltok, hbuf, s, cap, maxtiles);
        k_fc2<<<dim3(NE * maxtiles, DIM / 128), 256, 0, stream>>>(
            hbuf, W2b, b2, lcnt, loff, ltok, lwb, out, s, cap, maxtiles);
    }
    k_aux1<<<64, 256, 0, stream>>>(probs, tw2, tidx, partial, T);
    k_aux2<<<1, 64, 0, stream>>>(partial, out + (size_t)T * DIM, 64, T);
}

// Round 4
// 334.250 us; speedup vs baseline: 2.0860x; 1.5674x over previous
//
#include <hip/hip_runtime.h>
#include <hip/hip_bf16.h>
#include <math.h>

#define DIM 512
#define HID 2048
#define NE  8
#define CSTRIDE 32   // counter padding: 128B apart

typedef __attribute__((ext_vector_type(8))) short short8;
typedef __attribute__((ext_vector_type(4))) float f32x4;
typedef unsigned short ushort_t;

static __device__ __forceinline__ ushort_t f2bf(float f) {
    unsigned int x = __builtin_bit_cast(unsigned int, f);
    unsigned int lsb = (x >> 16) & 1u;
    x += 0x7fffu + lsb;
    return (ushort_t)(x >> 16);
}
static __device__ __forceinline__ float bf2f(ushort_t u) {
    unsigned int x = ((unsigned int)u) << 16;
    return __builtin_bit_cast(float, x);
}

// async global->LDS, 16B per lane. LDS dest is wave-uniform base + lane*16.
static __device__ __forceinline__ void gld16(const void* g, void* l) {
    __builtin_amdgcn_global_load_lds(
        (const __attribute__((address_space(1))) void*)g,
        (__attribute__((address_space(3))) void*)l,
        16, 0, 0);
}

// ---------------- fp32 -> bf16 bulk convert ----------------
__global__ void k_cvt(const float* __restrict__ src, ushort_t* __restrict__ dst, int n) {
    int i = blockIdx.x * blockDim.x + threadIdx.x;
    int stride = gridDim.x * blockDim.x;
    int n4 = n >> 2;
    for (int j = i; j < n4; j += stride) {
        float4 v = ((const float4*)src)[j];
        ushort4 o;
        o.x = f2bf(v.x); o.y = f2bf(v.y); o.z = f2bf(v.z); o.w = f2bf(v.w);
        ((ushort4*)dst)[j] = o;
    }
}

// ---------------- router: logits (f64), softmax, top-2 ----------------
__global__ __launch_bounds__(256) void k_router(const float* __restrict__ x,
    const float* __restrict__ Wr, ushort_t* __restrict__ xb,
    float* __restrict__ probs, int* __restrict__ tidx, float* __restrict__ tw, int T)
{
    int lane = threadIdx.x & 63;
    int t = blockIdx.x * 4 + (threadIdx.x >> 6);
    if (t >= T) return;
    const float* xr = x + (size_t)t * DIM;
    double acc[NE];
#pragma unroll
    for (int e = 0; e < NE; e++) acc[e] = 0.0;
    for (int i = lane; i < DIM; i += 64) {
        float xv = xr[i];
        xb[(size_t)t * DIM + i] = f2bf(xv);
        double xd = (double)xv;
#pragma unroll
        for (int e = 0; e < NE; e++) acc[e] += xd * (double)Wr[e * DIM + i];
    }
#pragma unroll
    for (int e = 0; e < NE; e++) {
#pragma unroll
        for (int off = 32; off > 0; off >>= 1) acc[e] += __shfl_xor(acc[e], off);
    }
    double mx = acc[0];
#pragma unroll
    for (int e = 1; e < NE; e++) mx = fmax(mx, acc[e]);
    double p[NE], sum = 0.0;
#pragma unroll
    for (int e = 0; e < NE; e++) { p[e] = exp(acc[e] - mx); sum += p[e]; }
    float pr[NE];
#pragma unroll
    for (int e = 0; e < NE; e++) pr[e] = (float)(p[e] / sum);
    if (lane < NE) probs[(size_t)t * NE + lane] = pr[lane];
    if (lane == 0) {
        int i1 = 0; float b1v = pr[0];
#pragma unroll
        for (int e = 1; e < NE; e++) if (pr[e] > b1v) { b1v = pr[e]; i1 = e; }
        int i2 = -1; float b2v = -1.f;
#pragma unroll
        for (int e = 0; e < NE; e++) if (e != i1 && pr[e] > b2v) { b2v = pr[e]; i2 = e; }
        float s2 = b1v + b2v + 1e-8f;
        tidx[t * 2] = i1; tidx[t * 2 + 1] = i2;
        tw[t * 2] = b1v / s2; tw[t * 2 + 1] = b2v / s2;
    }
}

// ---------------- per-(slot,expert) histogram: block-aggregated ----------------
__global__ __launch_bounds__(256) void k_hist(const int* __restrict__ tidx,
                                              int* __restrict__ cnt, int T) {
    __shared__ int h[16];
    if (threadIdx.x < 16) h[threadIdx.x] = 0;
    __syncthreads();
    int stride = gridDim.x * blockDim.x;
    for (int t = blockIdx.x * blockDim.x + threadIdx.x; t < T; t += stride) {
        atomicAdd(&h[tidx[t * 2]], 1);
        atomicAdd(&h[8 + tidx[t * 2 + 1]], 1);
    }
    __syncthreads();
    if (threadIdx.x < 16 && h[threadIdx.x] != 0)
        atomicAdd(&cnt[threadIdx.x * CSTRIDE], h[threadIdx.x]);
}

// ---------------- capacity keep (exact rank, per slot) + renormalize ----------------
__global__ void k_keep(const int* __restrict__ tidx, const float* __restrict__ tw,
                       const int* __restrict__ cnt, float* __restrict__ tw2, int T, int cap)
{
    int t = blockIdx.x * blockDim.x + threadIdx.x;
    if (t >= T) return;
    float wk[2];
#pragma unroll
    for (int s = 0; s < 2; s++) {
        int e = tidx[t * 2 + s];
        float w = tw[t * 2 + s];
        wk[s] = w;
        if (cnt[(s * NE + e) * CSTRIDE] > cap) {   // rare: exact stable-sort rank
            int rank = 0;
            for (int t2 = 0; t2 < T; t2++) {
                if (tidx[t2 * 2 + s] == e) {
                    float w2 = tw[t2 * 2 + s];
                    if (w2 > w || (w2 == w && t2 < t)) rank++;
                }
            }
            if (rank >= cap) wk[s] = 0.f;
        }
    }
    float denom = fmaxf(wk[0] + wk[1], 1e-8f);
    tw2[t * 2]     = wk[0] / denom;
    tw2[t * 2 + 1] = wk[1] / denom;
}

// ---------------- build MERGED per-expert token lists + pos map ----------------
// top-2 experts are distinct, so a token appears at most once per expert.
__global__ __launch_bounds__(256) void k_build(const int* __restrict__ tidx,
        const float* __restrict__ tw2, int* __restrict__ lcnt,
        int* __restrict__ ltok, int* __restrict__ pos, int T, int capM)
{
    __shared__ int h[NE];
    __shared__ int base[NE];
    if (threadIdx.x < NE) h[threadIdx.x] = 0;
    __syncthreads();
    int t = blockIdx.x * blockDim.x + threadIdx.x;
    int myE[2] = {-1, -1};
    int myp[2] = {0, 0};
    if (t < T) {
#pragma unroll
        for (int s = 0; s < 2; s++) {
            float w = tw2[t * 2 + s];
            if (w != 0.f) {
                int e = tidx[t * 2 + s];
                myE[s] = e;
                myp[s] = atomicAdd(&h[e], 1);   // LDS atomic
            }
        }
    }
    __syncthreads();
    if (threadIdx.x < NE)
        base[threadIdx.x] = (h[threadIdx.x] != 0)
            ? atomicAdd(&lcnt[threadIdx.x * CSTRIDE], h[threadIdx.x]) : 0;
    __syncthreads();
    if (t < T) {
#pragma unroll
        for (int s = 0; s < 2; s++) {
            if (myE[s] >= 0) {
                int p = base[myE[s]] + myp[s];   // p < capM guaranteed by capacity
                ltok[myE[s] * capM + p] = t;
                pos[t * 2 + s] = (myE[s] << 20) | p;
            } else {
                pos[t * 2 + s] = -1;
            }
        }
    }
}

// ---------------- 128-aligned prefix offsets (merged, 8 experts) ----------------
__global__ void k_off(const int* __restrict__ lcnt, int* __restrict__ loff) {
    if (threadIdx.x == 0 && blockIdx.x == 0) {
        int o = 0;
        for (int e = 0; e < NE; e++) {
            loff[e] = o;
            o += ((lcnt[e * CSTRIDE] + 127) >> 7) << 7;
        }
        loff[NE] = o;
    }
}

// ---------------- fc1: h = gelu(X @ W1^T + b1), dbuf-pipelined MFMA ----------------
__global__ __launch_bounds__(256) void k_fc1(
    const ushort_t* __restrict__ xb, const ushort_t* __restrict__ W1b,
    const float* __restrict__ b1, const int* __restrict__ lcnt,
    const int* __restrict__ loff, const int* __restrict__ ltok,
    ushort_t* __restrict__ hbuf, int capM)
{
    int bx = blockIdx.x;
    int e  = bx & 7;                 // expert == XCD residue: W1[e] stays in XCD-e L2
    int r  = bx >> 3;
    int mt = r >> 4;                 // HID/128 = 16 n-tiles, nt fastest for A-panel reuse
    int nt = r & 15;
    int cnt = lcnt[e * CSTRIDE];
    if (cnt > capM) cnt = capM;
    int m0 = mt * 128;
    if (m0 >= cnt) return;
    int n0 = nt * 128;
    const int* toks = ltok + e * capM;
    int hrow0 = loff[e] + m0;
    const ushort_t* Bsrc = W1b + (size_t)e * HID * DIM;

    __shared__ char smem[65536];
    char* As0 = smem;          char* Bs0 = smem + 16384;
    char* As1 = smem + 32768;  char* Bs1 = smem + 49152;

    int tid = threadIdx.x;
    int wave = tid >> 6, lane = tid & 63;
    int wm = wave >> 1, wn = wave & 1;

    const char* aSrc[4]; const char* bSrc[4]; int ldst[4];
#pragma unroll
    for (int i = 0; i < 4; i++) {
        int c = tid + 256 * i;             // chunk id 0..1023
        int row = c >> 3, cc = c & 7;
        int scc = cc ^ (row & 7);          // pre-swizzled source column chunk
        int gr = m0 + row;
        int tok = toks[gr < cnt ? gr : (cnt - 1)];
        aSrc[i] = (const char*)(xb + (size_t)tok * DIM + scc * 8);
        bSrc[i] = (const char*)(Bsrc + (size_t)(n0 + row) * DIM + scc * 8);
        ldst[i] = (i * 256 + wave * 64) * 16;   // wave-uniform LDS base
    }

    f32x4 acc[4][4];
#pragma unroll
    for (int a = 0; a < 4; a++)
#pragma unroll
        for (int b = 0; b < 4; b++) acc[a][b] = (f32x4){0.f, 0.f, 0.f, 0.f};

    int aRow = wm * 64 + (lane & 15);
    int bRow = wn * 64 + (lane & 15);
    int kq = lane >> 4;

    auto STAGE = [&](int kt, char* A, char* B) {
#pragma unroll
        for (int i = 0; i < 4; i++) {
            gld16(aSrc[i] + kt * 128, A + ldst[i]);
            gld16(bSrc[i] + kt * 128, B + ldst[i]);
        }
    };
    auto COMPUTE = [&](const char* A, const char* B) {
#pragma unroll
        for (int kk = 0; kk < 2; kk++) {
            int c16 = kk * 4 + kq;
            short8 af[4], bfr[4];
#pragma unroll
            for (int mf = 0; mf < 4; mf++) {
                int rr = aRow + mf * 16;
                af[mf] = *(const short8*)(A + rr * 128 + ((c16 ^ (rr & 7)) << 4));
            }
#pragma unroll
            for (int nf = 0; nf < 4; nf++) {
                int rr = bRow + nf * 16;
                bfr[nf] = *(const short8*)(B + rr * 128 + ((c16 ^ (rr & 7)) << 4));
            }
#pragma unroll
            for (int mf = 0; mf < 4; mf++)
#pragma unroll
                for (int nf = 0; nf < 4; nf++)
                    acc[mf][nf] = __builtin_amdgcn_mfma_f32_16x16x32_bf16(af[mf], bfr[nf], acc[mf][nf], 0, 0, 0);
        }
    };

    const int NT = DIM / 64;   // 8
    char *Ac = As0, *Bc = Bs0, *An = As1, *Bn = Bs1;
    STAGE(0, Ac, Bc);
    __syncthreads();           // drains vmcnt(0): tile 0 ready
    for (int kt = 0; kt < NT; kt++) {
        if (kt + 1 < NT) STAGE(kt + 1, An, Bn);   // prefetch overlaps MFMA below
        COMPUTE(Ac, Bc);
        __syncthreads();       // one barrier/K-step: drains vmcnt+lgkmcnt
        char* t0 = Ac; Ac = An; An = t0;
        char* t1 = Bc; Bc = Bn; Bn = t1;
    }

    const float* b1e = b1 + e * HID;
#pragma unroll
    for (int nf = 0; nf < 4; nf++) {
        int col = n0 + wn * 64 + nf * 16 + (lane & 15);
        float bias = b1e[col];
#pragma unroll
        for (int mf = 0; mf < 4; mf++) {
            int rbase = wm * 64 + mf * 16 + (lane >> 4) * 4;
#pragma unroll
            for (int rr = 0; rr < 4; rr++) {
                int rl = rbase + rr;
                float v = acc[mf][nf][rr] + bias;
                float g = 0.5f * v * (1.f + erff(v * 0.70710678118654752f));
                ushort_t o = ((m0 + rl) < cnt) ? f2bf(g) : (ushort_t)0;
                hbuf[(size_t)(hrow0 + rl) * HID + col] = o;
            }
        }
    }
}

// ---------------- fc2: ybuf[row] = H @ W2^T + b2 (unweighted, bf16) ----------------
__global__ __launch_bounds__(256) void k_fc2(
    const ushort_t* __restrict__ hbuf, const ushort_t* __restrict__ W2b,
    const float* __restrict__ b2, const int* __restrict__ lcnt,
    const int* __restrict__ loff, ushort_t* __restrict__ ybuf, int capM)
{
    int bx = blockIdx.x;
    int e  = bx & 7;
    int r  = bx >> 3;
    int mt = r >> 2;                 // DIM/128 = 4 n-tiles
    int nt = r & 3;
    int cnt = lcnt[e * CSTRIDE];
    if (cnt > capM) cnt = capM;
    int m0 = mt * 128;
    if (m0 >= cnt) return;
    int n0 = nt * 128;
    int hrow0 = loff[e] + m0;
    const ushort_t* Bsrc = W2b + (size_t)e * DIM * HID;

    __shared__ char smem[65536];
    char* As0 = smem;          char* Bs0 = smem + 16384;
    char* As1 = smem + 32768;  char* Bs1 = smem + 49152;

    int tid = threadIdx.x;
    int wave = tid >> 6, lane = tid & 63;
    int wm = wave >> 1, wn = wave & 1;

    const char* aSrc[4]; const char* bSrc[4]; int ldst[4];
#pragma unroll
    for (int i = 0; i < 4; i++) {
        int c = tid + 256 * i;
        int row = c >> 3, cc = c & 7;
        int scc = cc ^ (row & 7);
        aSrc[i] = (const char*)(hbuf + (size_t)(hrow0 + row) * HID + scc * 8);
        bSrc[i] = (const char*)(Bsrc + (size_t)(n0 + row) * HID + scc * 8);
        ldst[i] = (i * 256 + wave * 64) * 16;
    }

    f32x4 acc[4][4];
#pragma unroll
    for (int a = 0; a < 4; a++)
#pragma unroll
        for (int b = 0; b < 4; b++) acc[a][b] = (f32x4){0.f, 0.f, 0.f, 0.f};

    int aRow = wm * 64 + (lane & 15);
    int bRow = wn * 64 + (lane & 15);
    int kq = lane >> 4;

    auto STAGE = [&](int kt, char* A, char* B) {
#pragma unroll
        for (int i = 0; i < 4; i++) {
            gld16(aSrc[i] + kt * 128, A + ldst[i]);
            gld16(bSrc[i] + kt * 128, B + ldst[i]);
        }
    };
    auto COMPUTE = [&](const char* A, const char* B) {
#pragma unroll
        for (int kk = 0; kk < 2; kk++) {
            int c16 = kk * 4 + kq;
            short8 af[4], bfr[4];
#pragma unroll
            for (int mf = 0; mf < 4; mf++) {
                int rr = aRow + mf * 16;
                af[mf] = *(const short8*)(A + rr * 128 + ((c16 ^ (rr & 7)) << 4));
            }
#pragma unroll
            for (int nf = 0; nf < 4; nf++) {
                int rr = bRow + nf * 16;
                bfr[nf] = *(const short8*)(B + rr * 128 + ((c16 ^ (rr & 7)) << 4));
            }
#pragma unroll
            for (int mf = 0; mf < 4; mf++)
#pragma unroll
                for (int nf = 0; nf < 4; nf++)
                    acc[mf][nf] = __builtin_amdgcn_mfma_f32_16x16x32_bf16(af[mf], bfr[nf], acc[mf][nf], 0, 0, 0);
        }
    };

    const int NT = HID / 64;   // 32
    char *Ac = As0, *Bc = Bs0, *An = As1, *Bn = Bs1;
    STAGE(0, Ac, Bc);
    __syncthreads();
    for (int kt = 0; kt < NT; kt++) {
        if (kt + 1 < NT) STAGE(kt + 1, An, Bn);
        COMPUTE(Ac, Bc);
        __syncthreads();
        char* t0 = Ac; Ac = An; An = t0;
        char* t1 = Bc; Bc = Bn; Bn = t1;
    }

    const float* b2e = b2 + e * DIM;
#pragma unroll
    for (int nf = 0; nf < 4; nf++) {
        int col = n0 + wn * 64 + nf * 16 + (lane & 15);
        float bias = b2e[col];
#pragma unroll
        for (int mf = 0; mf < 4; mf++) {
            int rbase = wm * 64 + mf * 16 + (lane >> 4) * 4;
#pragma unroll
            for (int rr = 0; rr < 4; rr++) {
                int rl = rbase + rr;
                if ((m0 + rl) < cnt)
                    ybuf[(size_t)(hrow0 + rl) * DIM + col] = f2bf(acc[mf][nf][rr] + bias);
            }
        }
    }
}

// ---------------- combine: out[t] = w0*ybuf[row0] + w1*ybuf[row1] ----------------
__global__ __launch_bounds__(256) void k_comb(const ushort_t* __restrict__ ybuf,
    const float* __restrict__ tw2, const int* __restrict__ pos,
    const int* __restrict__ loff, float* __restrict__ out, int T, int capM)
{
    int wv = threadIdx.x >> 6, lane = threadIdx.x & 63;
    int t = blockIdx.x * 4 + wv;
    if (t >= T) return;
    float o[8];
#pragma unroll
    for (int j = 0; j < 8; j++) o[j] = 0.f;
#pragma unroll
    for (int s = 0; s < 2; s++) {
        int pk = pos[t * 2 + s];
        if (pk >= 0) {
            float w = tw2[t * 2 + s];
            int e = pk >> 20, p = pk & 0xFFFFF;
            int row = loff[e] + p;
            short8 y = *(const short8*)(ybuf + (size_t)row * DIM + lane * 8);
#pragma unroll
            for (int j = 0; j < 8; j++) o[j] += w * bf2f((ushort_t)y[j]);
        }
    }
    float4* dst = (float4*)(out + (size_t)t * DIM + lane * 8);
    dst[0] = (float4){o[0], o[1], o[2], o[3]};
    dst[1] = (float4){o[4], o[5], o[6], o[7]};
}

// ---------------- aux loss: two-stage deterministic reduce ----------------
__global__ __launch_bounds__(256) void k_aux1(const float* __restrict__ probs,
    const float* __restrict__ tw2, const int* __restrict__ tidx,
    float* __restrict__ partial, int T)
{
    __shared__ float red[256 * 16];
    float imp[NE], ld[NE];
#pragma unroll
    for (int e = 0; e < NE; e++) { imp[e] = 0.f; ld[e] = 0.f; }
    int stride = gridDim.x * blockDim.x;
    for (int t = blockIdx.x * blockDim.x + threadIdx.x; t < T; t += stride) {
#pragma unroll
        for (int e = 0; e < NE; e++) imp[e] += probs[(size_t)t * NE + e];
#pragma unroll
        for (int s = 0; s < 2; s++) ld[tidx[t * 2 + s]] += tw2[t * 2 + s];
    }
#pragma unroll
    for (int e = 0; e < NE; e++) {
        red[threadIdx.x * 16 + e] = imp[e];
        red[threadIdx.x * 16 + 8 + e] = ld[e];
    }
    __syncthreads();
    for (int off = 128; off > 0; off >>= 1) {
        if (threadIdx.x < off) {
#pragma unroll
            for (int j = 0; j < 16; j++)
                red[threadIdx.x * 16 + j] += red[(threadIdx.x + off) * 16 + j];
        }
        __syncthreads();
    }
    if (threadIdx.x < 16) partial[blockIdx.x * 16 + threadIdx.x] = red[threadIdx.x];
}

__global__ void k_aux2(const float* __restrict__ partial, float* __restrict__ outaux,
                       int nb, int T)
{
    __shared__ float s[16];
    if (threadIdx.x < 16) {
        float a = 0.f;
        for (int b = 0; b < nb; b++) a += partial[b * 16 + threadIdx.x];
        s[threadIdx.x] = a;
    }
    __syncthreads();
    if (threadIdx.x == 0) {
        float invT = 1.f / (float)T;
        float aux = 0.f;
        for (int e = 0; e < NE; e++)
            aux += (s[e] * invT) * (s[8 + e] * invT) * (float)NE;
        outaux[0] = aux;
    }
}

// ---------------- launch ----------------
extern "C" void kernel_launch(void* const* d_in, const int* in_sizes, int n_in,
                              void* d_out, int out_size, void* d_ws, size_t ws_size,
                              hipStream_t stream)
{
    const float* x  = (const float*)d_in[0];
    const float* Wr = (const float*)d_in[1];
    const float* W1 = (const float*)d_in[2];
    const float* b1 = (const float*)d_in[3];
    const float* W2 = (const float*)d_in[4];
    const float* b2 = (const float*)d_in[5];
    float* out = (float*)d_out;

    int T = in_sizes[0] / DIM;
    int cap = (int)(1.25 * (double)T * 2.0 / 8.0);
    if (cap < 1) cap = 1;
    int capM = 2 * cap; if (capM > T) capM = T;      // merged per-expert bound
    int mtmax = (capM + 127) / 128;

    char* w = (char*)d_ws;
    size_t off = 0;
    auto alloc = [&](size_t bytes) {
        char* p = w + off;
        off = (off + bytes + 255) & ~(size_t)255;
        return p;
    };
    // ybuf overlays xb+W1b (both dead before fc2 writes ybuf)
    size_t ybrows = (size_t)T * 2 + NE * 128;
    size_t ybbytes = ybrows * DIM * 2;
    ushort_t* ybuf = (ushort_t*)w;                    // offset 0
    ushort_t* xb   = (ushort_t*)alloc((size_t)T * DIM * 2);
    ushort_t* W1b  = (ushort_t*)alloc((size_t)NE * HID * DIM * 2);
    if (off < ybbytes) off = (ybbytes + 255) & ~(size_t)255;
    ushort_t* W2b  = (ushort_t*)alloc((size_t)NE * DIM * HID * 2);
    ushort_t* hbuf = (ushort_t*)alloc(ybrows * HID * 2);
    float* probs   = (float*)alloc((size_t)T * NE * 4);
    int*   tidx    = (int*)alloc((size_t)T * 2 * 4);
    float* tw      = (float*)alloc((size_t)T * 2 * 4);
    float* tw2     = (float*)alloc((size_t)T * 2 * 4);
    int*   pos     = (int*)alloc((size_t)T * 2 * 4);
    int*   cnt     = (int*)alloc(16 * CSTRIDE * 4);
    int*   lcnt    = (int*)alloc(NE * CSTRIDE * 4);
    int*   loff    = (int*)alloc((NE + 1) * 4);
    int*   ltok    = (int*)alloc((size_t)NE * capM * 4);
    float* partial = (float*)alloc(64 * 16 * 4);

    (void)hipMemsetAsync(cnt, 0, 16 * CSTRIDE * 4, stream);
    (void)hipMemsetAsync(lcnt, 0, NE * CSTRIDE * 4, stream);

    k_cvt<<<2048, 256, 0, stream>>>(W1, W1b, NE * HID * DIM);
    k_cvt<<<2048, 256, 0, stream>>>(W2, W2b, NE * DIM * HID);
    k_router<<<(T + 3) / 4, 256, 0, stream>>>(x, Wr, xb, probs, tidx, tw, T);
    k_hist<<<64, 256, 0, stream>>>(tidx, cnt, T);
    k_keep<<<(T + 255) / 256, 256, 0, stream>>>(tidx, tw, cnt, tw2, T, cap);
    k_build<<<(T + 255) / 256, 256, 0, stream>>>(tidx, tw2, lcnt, ltok, pos, T, capM);
    k_off<<<1, 64, 0, stream>>>(lcnt, loff);

    k_fc1<<<NE * mtmax * (HID / 128), 256, 0, stream>>>(
        xb, W1b, b1, lcnt, loff, ltok, hbuf, capM);
    k_fc2<<<NE * mtmax * (DIM / 128), 256, 0, stream>>>(
        hbuf, W2b, b2, lcnt, loff, ybuf, capM);
    k_comb<<<(T + 3) / 4, 256, 0, stream>>>(ybuf, tw2, pos, loff, out, T, capM);

    k_aux1<<<64, 256, 0, stream>>>(probs, tw2, tidx, partial, T);
    k_aux2<<<1, 64, 0, stream>>>(partial, out + (size_t)T * DIM, 64, T);
}

// Round 5
// 306.563 us; speedup vs baseline: 2.2744x; 1.0903x over previous
//
#include <hip/hip_runtime.h>
#include <hip/hip_bf16.h>
#include <math.h>

#define DIM 512
#define HID 2048
#define NE  8
#define CSTRIDE 32   // counter padding: 128B apart

typedef __attribute__((ext_vector_type(8))) short short8;
typedef __attribute__((ext_vector_type(4))) float f32x4;
typedef unsigned short ushort_t;

static __device__ __forceinline__ ushort_t f2bf(float f) {
    unsigned int x = __builtin_bit_cast(unsigned int, f);
    unsigned int lsb = (x >> 16) & 1u;
    x += 0x7fffu + lsb;
    return (ushort_t)(x >> 16);
}
static __device__ __forceinline__ float bf2f(ushort_t u) {
    unsigned int x = ((unsigned int)u) << 16;
    return __builtin_bit_cast(float, x);
}

// exact-gelu via A&S 7.1.26 erf approx (|err|<=1.5e-7, << bf16 rounding)
static __device__ __forceinline__ float fast_gelu(float v) {
    float u = v * 0.70710678118654752f;
    float s = fabsf(u);
    float t = __builtin_amdgcn_rcpf(1.f + 0.3275911f * s);
    float poly = ((((1.061405429f * t - 1.453152027f) * t + 1.421413741f) * t
                   - 0.284496736f) * t + 0.254829592f) * t;
    float e = __expf(-s * s);
    float erfv = copysignf(1.f - poly * e, u);
    return 0.5f * v * (1.f + erfv);
}

// async global->LDS, 16B per lane. LDS dest is wave-uniform base + lane*16.
static __device__ __forceinline__ void gld16(const void* g, void* l) {
    __builtin_amdgcn_global_load_lds(
        (const __attribute__((address_space(1))) void*)g,
        (__attribute__((address_space(3))) void*)l,
        16, 0, 0);
}

// ---------------- fp32 -> bf16 bulk convert ----------------
__global__ void k_cvt(const float* __restrict__ src, ushort_t* __restrict__ dst, int n) {
    int i = blockIdx.x * blockDim.x + threadIdx.x;
    int stride = gridDim.x * blockDim.x;
    int n4 = n >> 2;
    for (int j = i; j < n4; j += stride) {
        float4 v = ((const float4*)src)[j];
        ushort4 o;
        o.x = f2bf(v.x); o.y = f2bf(v.y); o.z = f2bf(v.z); o.w = f2bf(v.w);
        ((ushort4*)dst)[j] = o;
    }
}

// ---------------- router: logits (f64), softmax, top-2 ----------------
__global__ __launch_bounds__(256) void k_router(const float* __restrict__ x,
    const float* __restrict__ Wr, ushort_t* __restrict__ xb,
    float* __restrict__ probs, int* __restrict__ tidx, float* __restrict__ tw, int T)
{
    int lane = threadIdx.x & 63;
    int t = blockIdx.x * 4 + (threadIdx.x >> 6);
    if (t >= T) return;
    const float* xr = x + (size_t)t * DIM;
    double acc[NE];
#pragma unroll
    for (int e = 0; e < NE; e++) acc[e] = 0.0;
    for (int i = lane; i < DIM; i += 64) {
        float xv = xr[i];
        xb[(size_t)t * DIM + i] = f2bf(xv);
        double xd = (double)xv;
#pragma unroll
        for (int e = 0; e < NE; e++) acc[e] += xd * (double)Wr[e * DIM + i];
    }
#pragma unroll
    for (int e = 0; e < NE; e++) {
#pragma unroll
        for (int off = 32; off > 0; off >>= 1) acc[e] += __shfl_xor(acc[e], off);
    }
    double mx = acc[0];
#pragma unroll
    for (int e = 1; e < NE; e++) mx = fmax(mx, acc[e]);
    double p[NE], sum = 0.0;
#pragma unroll
    for (int e = 0; e < NE; e++) { p[e] = exp(acc[e] - mx); sum += p[e]; }
    float pr[NE];
#pragma unroll
    for (int e = 0; e < NE; e++) pr[e] = (float)(p[e] / sum);
    if (lane < NE) probs[(size_t)t * NE + lane] = pr[lane];
    if (lane == 0) {
        int i1 = 0; float b1v = pr[0];
#pragma unroll
        for (int e = 1; e < NE; e++) if (pr[e] > b1v) { b1v = pr[e]; i1 = e; }
        int i2 = -1; float b2v = -1.f;
#pragma unroll
        for (int e = 0; e < NE; e++) if (e != i1 && pr[e] > b2v) { b2v = pr[e]; i2 = e; }
        float s2 = b1v + b2v + 1e-8f;
        tidx[t * 2] = i1; tidx[t * 2 + 1] = i2;
        tw[t * 2] = b1v / s2; tw[t * 2 + 1] = b2v / s2;
    }
}

// ---------------- per-(slot,expert) histogram: block-aggregated ----------------
__global__ __launch_bounds__(256) void k_hist(const int* __restrict__ tidx,
                                              int* __restrict__ cnt, int T) {
    __shared__ int h[16];
    if (threadIdx.x < 16) h[threadIdx.x] = 0;
    __syncthreads();
    int stride = gridDim.x * blockDim.x;
    for (int t = blockIdx.x * blockDim.x + threadIdx.x; t < T; t += stride) {
        atomicAdd(&h[tidx[t * 2]], 1);
        atomicAdd(&h[8 + tidx[t * 2 + 1]], 1);
    }
    __syncthreads();
    if (threadIdx.x < 16 && h[threadIdx.x] != 0)
        atomicAdd(&cnt[threadIdx.x * CSTRIDE], h[threadIdx.x]);
}

// ---------------- capacity keep (exact rank, per slot) + renormalize ----------------
__global__ void k_keep(const int* __restrict__ tidx, const float* __restrict__ tw,
                       const int* __restrict__ cnt, float* __restrict__ tw2, int T, int cap)
{
    int t = blockIdx.x * blockDim.x + threadIdx.x;
    if (t >= T) return;
    float wk[2];
#pragma unroll
    for (int s = 0; s < 2; s++) {
        int e = tidx[t * 2 + s];
        float w = tw[t * 2 + s];
        wk[s] = w;
        if (cnt[(s * NE + e) * CSTRIDE] > cap) {   // rare: exact stable-sort rank
            int rank = 0;
            for (int t2 = 0; t2 < T; t2++) {
                if (tidx[t2 * 2 + s] == e) {
                    float w2 = tw[t2 * 2 + s];
                    if (w2 > w || (w2 == w && t2 < t)) rank++;
                }
            }
            if (rank >= cap) wk[s] = 0.f;
        }
    }
    float denom = fmaxf(wk[0] + wk[1], 1e-8f);
    tw2[t * 2]     = wk[0] / denom;
    tw2[t * 2 + 1] = wk[1] / denom;
}

// ---------------- build MERGED per-expert token lists + pos map ----------------
__global__ __launch_bounds__(256) void k_build(const int* __restrict__ tidx,
        const float* __restrict__ tw2, int* __restrict__ lcnt,
        int* __restrict__ ltok, int* __restrict__ pos, int T, int capM)
{
    __shared__ int h[NE];
    __shared__ int base[NE];
    if (threadIdx.x < NE) h[threadIdx.x] = 0;
    __syncthreads();
    int t = blockIdx.x * blockDim.x + threadIdx.x;
    int myE[2] = {-1, -1};
    int myp[2] = {0, 0};
    if (t < T) {
#pragma unroll
        for (int s = 0; s < 2; s++) {
            float w = tw2[t * 2 + s];
            if (w != 0.f) {
                int e = tidx[t * 2 + s];
                myE[s] = e;
                myp[s] = atomicAdd(&h[e], 1);   // LDS atomic
            }
        }
    }
    __syncthreads();
    if (threadIdx.x < NE)
        base[threadIdx.x] = (h[threadIdx.x] != 0)
            ? atomicAdd(&lcnt[threadIdx.x * CSTRIDE], h[threadIdx.x]) : 0;
    __syncthreads();
    if (t < T) {
#pragma unroll
        for (int s = 0; s < 2; s++) {
            if (myE[s] >= 0) {
                int p = base[myE[s]] + myp[s];
                ltok[myE[s] * capM + p] = t;
                pos[t * 2 + s] = (myE[s] << 20) | p;
            } else {
                pos[t * 2 + s] = -1;
            }
        }
    }
}

// ---------------- 128-aligned prefix offsets (merged, 8 experts) ----------------
__global__ void k_off(const int* __restrict__ lcnt, int* __restrict__ loff) {
    if (threadIdx.x == 0 && blockIdx.x == 0) {
        int o = 0;
        for (int e = 0; e < NE; e++) {
            loff[e] = o;
            o += ((lcnt[e * CSTRIDE] + 127) >> 7) << 7;
        }
        loff[NE] = o;
    }
}

// ---------------- fc1: h = gelu(X @ W1^T + b1), dbuf-pipelined MFMA ----------------
// Swapped-operand MFMA: D reg index walks 4 consecutive OUTPUT COLUMNS of one row
// -> epilogue packs ushort4 (8B stores) and loads bias as float4.
__global__ __launch_bounds__(256) void k_fc1(
    const ushort_t* __restrict__ xb, const ushort_t* __restrict__ W1b,
    const float* __restrict__ b1, const int* __restrict__ lcnt,
    const int* __restrict__ loff, const int* __restrict__ ltok,
    ushort_t* __restrict__ hbuf, int capM)
{
    int bx = blockIdx.x;
    int e  = bx & 7;                 // expert == XCD residue
    int r  = bx >> 3;
    int mt = r >> 4;
    int nt = r & 15;
    int cnt = lcnt[e * CSTRIDE];
    if (cnt > capM) cnt = capM;
    int m0 = mt * 128;
    if (m0 >= cnt) return;
    int n0 = nt * 128;
    const int* toks = ltok + e * capM;
    int hrow0 = loff[e] + m0;
    const ushort_t* Bsrc = W1b + (size_t)e * HID * DIM;

    __shared__ char smem[65536];
    char* As0 = smem;          char* Bs0 = smem + 16384;
    char* As1 = smem + 32768;  char* Bs1 = smem + 49152;

    int tid = threadIdx.x;
    int wave = tid >> 6, lane = tid & 63;
    int wm = wave >> 1, wn = wave & 1;

    const char* aSrc[4]; const char* bSrc[4]; int ldst[4];
#pragma unroll
    for (int i = 0; i < 4; i++) {
        int c = tid + 256 * i;
        int row = c >> 3, cc = c & 7;
        int scc = cc ^ (row & 7);          // pre-swizzled source column chunk
        int gr = m0 + row;
        int tok = toks[gr < cnt ? gr : (cnt - 1)];
        aSrc[i] = (const char*)(xb + (size_t)tok * DIM + scc * 8);
        bSrc[i] = (const char*)(Bsrc + (size_t)(n0 + row) * DIM + scc * 8);
        ldst[i] = (i * 256 + wave * 64) * 16;
    }

    f32x4 acc[4][4];
#pragma unroll
    for (int a = 0; a < 4; a++)
#pragma unroll
        for (int b = 0; b < 4; b++) acc[a][b] = (f32x4){0.f, 0.f, 0.f, 0.f};

    int aRow = wm * 64 + (lane & 15);
    int bRow = wn * 64 + (lane & 15);
    int kq = lane >> 4;

    auto STAGE = [&](int kt, char* A, char* B) {
#pragma unroll
        for (int i = 0; i < 4; i++) {
            gld16(aSrc[i] + kt * 128, A + ldst[i]);
            gld16(bSrc[i] + kt * 128, B + ldst[i]);
        }
    };
    auto COMPUTE = [&](const char* A, const char* B) {
#pragma unroll
        for (int kk = 0; kk < 2; kk++) {
            int c16 = kk * 4 + kq;
            short8 af[4], bfr[4];
#pragma unroll
            for (int mf = 0; mf < 4; mf++) {
                int rr = aRow + mf * 16;
                af[mf] = *(const short8*)(A + rr * 128 + ((c16 ^ (rr & 7)) << 4));
            }
#pragma unroll
            for (int nf = 0; nf < 4; nf++) {
                int rr = bRow + nf * 16;
                bfr[nf] = *(const short8*)(B + rr * 128 + ((c16 ^ (rr & 7)) << 4));
            }
#pragma unroll
            for (int mf = 0; mf < 4; mf++)
#pragma unroll
                for (int nf = 0; nf < 4; nf++)
                    acc[mf][nf] = __builtin_amdgcn_mfma_f32_16x16x32_bf16(bfr[nf], af[mf], acc[mf][nf], 0, 0, 0);
        }
    };

    const int NT = DIM / 64;   // 8
    char *Ac = As0, *Bc = Bs0, *An = As1, *Bn = Bs1;
    STAGE(0, Ac, Bc);
    __syncthreads();
    for (int kt = 0; kt < NT; kt++) {
        if (kt + 1 < NT) STAGE(kt + 1, An, Bn);
        COMPUTE(Ac, Bc);
        __syncthreads();
        char* t0 = Ac; Ac = An; An = t0;
        char* t1 = Bc; Bc = Bn; Bn = t1;
    }

    // epilogue: row = wm*64+mf*16+(lane&15); cols = n0+wn*64+nf*16+(lane>>4)*4 + r
    const float* b1e = b1 + e * HID;
    int mlocal = wm * 64 + (lane & 15);
    int nbase0 = n0 + wn * 64 + (lane >> 4) * 4;
#pragma unroll
    for (int mf = 0; mf < 4; mf++) {
        int mrow = mlocal + mf * 16;
        bool valid = (m0 + mrow) < cnt;
        ushort_t* dst = hbuf + (size_t)(hrow0 + mrow) * HID;
#pragma unroll
        for (int nf = 0; nf < 4; nf++) {
            int nc = nbase0 + nf * 16;
            float4 bias4 = *(const float4*)(b1e + nc);
            ushort4 o;
            o.x = f2bf(fast_gelu(acc[mf][nf][0] + bias4.x));
            o.y = f2bf(fast_gelu(acc[mf][nf][1] + bias4.y));
            o.z = f2bf(fast_gelu(acc[mf][nf][2] + bias4.z));
            o.w = f2bf(fast_gelu(acc[mf][nf][3] + bias4.w));
            if (valid) *(ushort4*)(dst + nc) = o;
        }
    }
}

// ---------------- fc2: ybuf[row] = H @ W2^T + b2 (unweighted, bf16) ----------------
__global__ __launch_bounds__(256) void k_fc2(
    const ushort_t* __restrict__ hbuf, const ushort_t* __restrict__ W2b,
    const float* __restrict__ b2, const int* __restrict__ lcnt,
    const int* __restrict__ loff, ushort_t* __restrict__ ybuf, int capM)
{
    int bx = blockIdx.x;
    int e  = bx & 7;
    int r  = bx >> 3;
    int mt = r >> 2;
    int nt = r & 3;
    int cnt = lcnt[e * CSTRIDE];
    if (cnt > capM) cnt = capM;
    int m0 = mt * 128;
    if (m0 >= cnt) return;
    int n0 = nt * 128;
    int hrow0 = loff[e] + m0;
    const ushort_t* Bsrc = W2b + (size_t)e * DIM * HID;

    __shared__ char smem[65536];
    char* As0 = smem;          char* Bs0 = smem + 16384;
    char* As1 = smem + 32768;  char* Bs1 = smem + 49152;

    int tid = threadIdx.x;
    int wave = tid >> 6, lane = tid & 63;
    int wm = wave >> 1, wn = wave & 1;

    const char* aSrc[4]; const char* bSrc[4]; int ldst[4];
#pragma unroll
    for (int i = 0; i < 4; i++) {
        int c = tid + 256 * i;
        int row = c >> 3, cc = c & 7;
        int scc = cc ^ (row & 7);
        aSrc[i] = (const char*)(hbuf + (size_t)(hrow0 + row) * HID + scc * 8);
        bSrc[i] = (const char*)(Bsrc + (size_t)(n0 + row) * HID + scc * 8);
        ldst[i] = (i * 256 + wave * 64) * 16;
    }

    f32x4 acc[4][4];
#pragma unroll
    for (int a = 0; a < 4; a++)
#pragma unroll
        for (int b = 0; b < 4; b++) acc[a][b] = (f32x4){0.f, 0.f, 0.f, 0.f};

    int aRow = wm * 64 + (lane & 15);
    int bRow = wn * 64 + (lane & 15);
    int kq = lane >> 4;

    auto STAGE = [&](int kt, char* A, char* B) {
#pragma unroll
        for (int i = 0; i < 4; i++) {
            gld16(aSrc[i] + kt * 128, A + ldst[i]);
            gld16(bSrc[i] + kt * 128, B + ldst[i]);
        }
    };
    auto COMPUTE = [&](const char* A, const char* B) {
#pragma unroll
        for (int kk = 0; kk < 2; kk++) {
            int c16 = kk * 4 + kq;
            short8 af[4], bfr[4];
#pragma unroll
            for (int mf = 0; mf < 4; mf++) {
                int rr = aRow + mf * 16;
                af[mf] = *(const short8*)(A + rr * 128 + ((c16 ^ (rr & 7)) << 4));
            }
#pragma unroll
            for (int nf = 0; nf < 4; nf++) {
                int rr = bRow + nf * 16;
                bfr[nf] = *(const short8*)(B + rr * 128 + ((c16 ^ (rr & 7)) << 4));
            }
#pragma unroll
            for (int mf = 0; mf < 4; mf++)
#pragma unroll
                for (int nf = 0; nf < 4; nf++)
                    acc[mf][nf] = __builtin_amdgcn_mfma_f32_16x16x32_bf16(bfr[nf], af[mf], acc[mf][nf], 0, 0, 0);
        }
    };

    const int NT = HID / 64;   // 32
    char *Ac = As0, *Bc = Bs0, *An = As1, *Bn = Bs1;
    STAGE(0, Ac, Bc);
    __syncthreads();
    for (int kt = 0; kt < NT; kt++) {
        if (kt + 1 < NT) STAGE(kt + 1, An, Bn);
        COMPUTE(Ac, Bc);
        __syncthreads();
        char* t0 = Ac; Ac = An; An = t0;
        char* t1 = Bc; Bc = Bn; Bn = t1;
    }

    const float* b2e = b2 + e * DIM;
    int mlocal = wm * 64 + (lane & 15);
    int nbase0 = n0 + wn * 64 + (lane >> 4) * 4;
#pragma unroll
    for (int mf = 0; mf < 4; mf++) {
        int mrow = mlocal + mf * 16;
        bool valid = (m0 + mrow) < cnt;
        ushort_t* dst = ybuf + (size_t)(hrow0 + mrow) * DIM;
#pragma unroll
        for (int nf = 0; nf < 4; nf++) {
            int nc = nbase0 + nf * 16;
            float4 bias4 = *(const float4*)(b2e + nc);
            ushort4 o;
            o.x = f2bf(acc[mf][nf][0] + bias4.x);
            o.y = f2bf(acc[mf][nf][1] + bias4.y);
            o.z = f2bf(acc[mf][nf][2] + bias4.z);
            o.w = f2bf(acc[mf][nf][3] + bias4.w);
            if (valid) *(ushort4*)(dst + nc) = o;
        }
    }
}

// ---------------- combine: out[t] = w0*ybuf[row0] + w1*ybuf[row1] ----------------
__global__ __launch_bounds__(256) void k_comb(const ushort_t* __restrict__ ybuf,
    const float* __restrict__ tw2, const int* __restrict__ pos,
    const int* __restrict__ loff, float* __restrict__ out, int T, int capM)
{
    int wv = threadIdx.x >> 6, lane = threadIdx.x & 63;
    int t = blockIdx.x * 4 + wv;
    if (t >= T) return;
    float o[8];
#pragma unroll
    for (int j = 0; j < 8; j++) o[j] = 0.f;
#pragma unroll
    for (int s = 0; s < 2; s++) {
        int pk = pos[t * 2 + s];
        if (pk >= 0) {
            float w = tw2[t * 2 + s];
            int e = pk >> 20, p = pk & 0xFFFFF;
            int row = loff[e] + p;
            short8 y = *(const short8*)(ybuf + (size_t)row * DIM + lane * 8);
#pragma unroll
            for (int j = 0; j < 8; j++) o[j] += w * bf2f((ushort_t)y[j]);
        }
    }
    float4* dst = (float4*)(out + (size_t)t * DIM + lane * 8);
    dst[0] = (float4){o[0], o[1], o[2], o[3]};
    dst[1] = (float4){o[4], o[5], o[6], o[7]};
}

// ---------------- aux loss: two-stage deterministic reduce ----------------
__global__ __launch_bounds__(256) void k_aux1(const float* __restrict__ probs,
    const float* __restrict__ tw2, const int* __restrict__ tidx,
    float* __restrict__ partial, int T)
{
    __shared__ float red[256 * 16];
    float imp[NE], ld[NE];
#pragma unroll
    for (int e = 0; e < NE; e++) { imp[e] = 0.f; ld[e] = 0.f; }
    int stride = gridDim.x * blockDim.x;
    for (int t = blockIdx.x * blockDim.x + threadIdx.x; t < T; t += stride) {
#pragma unroll
        for (int e = 0; e < NE; e++) imp[e] += probs[(size_t)t * NE + e];
#pragma unroll
        for (int s = 0; s < 2; s++) ld[tidx[t * 2 + s]] += tw2[t * 2 + s];
    }
#pragma unroll
    for (int e = 0; e < NE; e++) {
        red[threadIdx.x * 16 + e] = imp[e];
        red[threadIdx.x * 16 + 8 + e] = ld[e];
    }
    __syncthreads();
    for (int off = 128; off > 0; off >>= 1) {
        if (threadIdx.x < off) {
#pragma unroll
            for (int j = 0; j < 16; j++)
                red[threadIdx.x * 16 + j] += red[(threadIdx.x + off) * 16 + j];
        }
        __syncthreads();
    }
    if (threadIdx.x < 16) partial[blockIdx.x * 16 + threadIdx.x] = red[threadIdx.x];
}

__global__ void k_aux2(const float* __restrict__ partial, float* __restrict__ outaux,
                       int nb, int T)
{
    __shared__ float s[16];
    if (threadIdx.x < 16) {
        float a = 0.f;
        for (int b = 0; b < nb; b++) a += partial[b * 16 + threadIdx.x];
        s[threadIdx.x] = a;
    }
    __syncthreads();
    if (threadIdx.x == 0) {
        float invT = 1.f / (float)T;
        float aux = 0.f;
        for (int e = 0; e < NE; e++)
            aux += (s[e] * invT) * (s[8 + e] * invT) * (float)NE;
        outaux[0] = aux;
    }
}

// ---------------- launch ----------------
extern "C" void kernel_launch(void* const* d_in, const int* in_sizes, int n_in,
                              void* d_out, int out_size, void* d_ws, size_t ws_size,
                              hipStream_t stream)
{
    const float* x  = (const float*)d_in[0];
    const float* Wr = (const float*)d_in[1];
    const float* W1 = (const float*)d_in[2];
    const float* b1 = (const float*)d_in[3];
    const float* W2 = (const float*)d_in[4];
    const float* b2 = (const float*)d_in[5];
    float* out = (float*)d_out;

    int T = in_sizes[0] / DIM;
    int cap = (int)(1.25 * (double)T * 2.0 / 8.0);
    if (cap < 1) cap = 1;
    int capM = 2 * cap; if (capM > T) capM = T;      // merged per-expert bound
    int mtmax = (capM + 127) / 128;

    char* w = (char*)d_ws;
    size_t off = 0;
    auto alloc = [&](size_t bytes) {
        char* p = w + off;
        off = (off + bytes + 255) & ~(size_t)255;
        return p;
    };
    // ybuf overlays xb+W1b (both dead before fc2 writes ybuf)
    size_t ybrows = (size_t)T * 2 + NE * 128;
    size_t ybbytes = ybrows * DIM * 2;
    ushort_t* ybuf = (ushort_t*)w;                    // offset 0
    ushort_t* xb   = (ushort_t*)alloc((size_t)T * DIM * 2);
    ushort_t* W1b  = (ushort_t*)alloc((size_t)NE * HID * DIM * 2);
    if (off < ybbytes) off = (ybbytes + 255) & ~(size_t)255;
    ushort_t* W2b  = (ushort_t*)alloc((size_t)NE * DIM * HID * 2);
    ushort_t* hbuf = (ushort_t*)alloc(ybrows * HID * 2);
    float* probs   = (float*)alloc((size_t)T * NE * 4);
    int*   tidx    = (int*)alloc((size_t)T * 2 * 4);
    float* tw      = (float*)alloc((size_t)T * 2 * 4);
    float* tw2     = (float*)alloc((size_t)T * 2 * 4);
    int*   pos     = (int*)alloc((size_t)T * 2 * 4);
    int*   cnt     = (int*)alloc(16 * CSTRIDE * 4);
    int*   lcnt    = (int*)alloc(NE * CSTRIDE * 4);
    int*   loff    = (int*)alloc((NE + 1) * 4);
    int*   ltok    = (int*)alloc((size_t)NE * capM * 4);
    float* partial = (float*)alloc(64 * 16 * 4);

    (void)hipMemsetAsync(cnt, 0, 16 * CSTRIDE * 4, stream);
    (void)hipMemsetAsync(lcnt, 0, NE * CSTRIDE * 4, stream);

    k_cvt<<<2048, 256, 0, stream>>>(W1, W1b, NE * HID * DIM);
    k_cvt<<<2048, 256, 0, stream>>>(W2, W2b, NE * DIM * HID);
    k_router<<<(T + 3) / 4, 256, 0, stream>>>(x, Wr, xb, probs, tidx, tw, T);
    k_hist<<<64, 256, 0, stream>>>(tidx, cnt, T);
    k_keep<<<(T + 255) / 256, 256, 0, stream>>>(tidx, tw, cnt, tw2, T, cap);
    k_build<<<(T + 255) / 256, 256, 0, stream>>>(tidx, tw2, lcnt, ltok, pos, T, capM);
    k_off<<<1, 64, 0, stream>>>(lcnt, loff);

    k_fc1<<<NE * mtmax * (HID / 128), 256, 0, stream>>>(
        xb, W1b, b1, lcnt, loff, ltok, hbuf, capM);
    k_fc2<<<NE * mtmax * (DIM / 128), 256, 0, stream>>>(
        hbuf, W2b, b2, lcnt, loff, ybuf, capM);
    k_comb<<<(T + 3) / 4, 256, 0, stream>>>(ybuf, tw2, pos, loff, out, T, capM);

    k_aux1<<<64, 256, 0, stream>>>(probs, tw2, tidx, partial, T);
    k_aux2<<<1, 64, 0, stream>>>(partial, out + (size_t)T * DIM, 64, T);
}

// Round 6
// 301.018 us; speedup vs baseline: 2.3163x; 1.0184x over previous
//
#include <hip/hip_runtime.h>
#include <hip/hip_bf16.h>
#include <math.h>

#define DIM 512
#define HID 2048
#define NE  8
#define CSTRIDE 32   // counter padding: 128B apart

typedef __attribute__((ext_vector_type(8))) short short8;
typedef __attribute__((ext_vector_type(4))) float f32x4;
typedef unsigned short ushort_t;

static __device__ __forceinline__ ushort_t f2bf(float f) {
    unsigned int x = __builtin_bit_cast(unsigned int, f);
    unsigned int lsb = (x >> 16) & 1u;
    x += 0x7fffu + lsb;
    return (ushort_t)(x >> 16);
}
static __device__ __forceinline__ float bf2f(ushort_t u) {
    unsigned int x = ((unsigned int)u) << 16;
    return __builtin_bit_cast(float, x);
}

// exact-gelu via A&S 7.1.26 erf approx (|err|<=1.5e-7, << bf16 rounding)
static __device__ __forceinline__ float fast_gelu(float v) {
    float u = v * 0.70710678118654752f;
    float s = fabsf(u);
    float t = __builtin_amdgcn_rcpf(1.f + 0.3275911f * s);
    float poly = ((((1.061405429f * t - 1.453152027f) * t + 1.421413741f) * t
                   - 0.284496736f) * t + 0.254829592f) * t;
    float e = __expf(-s * s);
    float erfv = copysignf(1.f - poly * e, u);
    return 0.5f * v * (1.f + erfv);
}

// async global->LDS, 16B per lane. LDS dest is wave-uniform base + lane*16.
static __device__ __forceinline__ void gld16(const void* g, void* l) {
    __builtin_amdgcn_global_load_lds(
        (const __attribute__((address_space(1))) void*)g,
        (__attribute__((address_space(3))) void*)l,
        16, 0, 0);
}

// ---------------- fp32 -> bf16 bulk convert ----------------
__global__ void k_cvt(const float* __restrict__ src, ushort_t* __restrict__ dst, int n) {
    int i = blockIdx.x * blockDim.x + threadIdx.x;
    int stride = gridDim.x * blockDim.x;
    int n4 = n >> 2;
    for (int j = i; j < n4; j += stride) {
        float4 v = ((const float4*)src)[j];
        ushort4 o;
        o.x = f2bf(v.x); o.y = f2bf(v.y); o.z = f2bf(v.z); o.w = f2bf(v.w);
        ((ushort4*)dst)[j] = o;
    }
}

// ---------------- router: logits (f64), softmax, top-2 ----------------
__global__ __launch_bounds__(256) void k_router(const float* __restrict__ x,
    const float* __restrict__ Wr, ushort_t* __restrict__ xb,
    float* __restrict__ probs, int* __restrict__ tidx, float* __restrict__ tw, int T)
{
    int lane = threadIdx.x & 63;
    int t = blockIdx.x * 4 + (threadIdx.x >> 6);
    if (t >= T) return;
    const float* xr = x + (size_t)t * DIM;
    double acc[NE];
#pragma unroll
    for (int e = 0; e < NE; e++) acc[e] = 0.0;
    for (int i = lane; i < DIM; i += 64) {
        float xv = xr[i];
        xb[(size_t)t * DIM + i] = f2bf(xv);
        double xd = (double)xv;
#pragma unroll
        for (int e = 0; e < NE; e++) acc[e] += xd * (double)Wr[e * DIM + i];
    }
#pragma unroll
    for (int e = 0; e < NE; e++) {
#pragma unroll
        for (int off = 32; off > 0; off >>= 1) acc[e] += __shfl_xor(acc[e], off);
    }
    double mx = acc[0];
#pragma unroll
    for (int e = 1; e < NE; e++) mx = fmax(mx, acc[e]);
    double p[NE], sum = 0.0;
#pragma unroll
    for (int e = 0; e < NE; e++) { p[e] = exp(acc[e] - mx); sum += p[e]; }
    float pr[NE];
#pragma unroll
    for (int e = 0; e < NE; e++) pr[e] = (float)(p[e] / sum);
    if (lane < NE) probs[(size_t)t * NE + lane] = pr[lane];
    if (lane == 0) {
        int i1 = 0; float b1v = pr[0];
#pragma unroll
        for (int e = 1; e < NE; e++) if (pr[e] > b1v) { b1v = pr[e]; i1 = e; }
        int i2 = -1; float b2v = -1.f;
#pragma unroll
        for (int e = 0; e < NE; e++) if (e != i1 && pr[e] > b2v) { b2v = pr[e]; i2 = e; }
        float s2 = b1v + b2v + 1e-8f;
        tidx[t * 2] = i1; tidx[t * 2 + 1] = i2;
        tw[t * 2] = b1v / s2; tw[t * 2 + 1] = b2v / s2;
    }
}

// ---------------- per-(slot,expert) histogram: block-aggregated ----------------
__global__ __launch_bounds__(256) void k_hist(const int* __restrict__ tidx,
                                              int* __restrict__ cnt, int T) {
    __shared__ int h[16];
    if (threadIdx.x < 16) h[threadIdx.x] = 0;
    __syncthreads();
    int stride = gridDim.x * blockDim.x;
    for (int t = blockIdx.x * blockDim.x + threadIdx.x; t < T; t += stride) {
        atomicAdd(&h[tidx[t * 2]], 1);
        atomicAdd(&h[8 + tidx[t * 2 + 1]], 1);
    }
    __syncthreads();
    if (threadIdx.x < 16 && h[threadIdx.x] != 0)
        atomicAdd(&cnt[threadIdx.x * CSTRIDE], h[threadIdx.x]);
}

// ---------------- capacity keep (exact rank, per slot) + renormalize ----------------
__global__ void k_keep(const int* __restrict__ tidx, const float* __restrict__ tw,
                       const int* __restrict__ cnt, float* __restrict__ tw2, int T, int cap)
{
    int t = blockIdx.x * blockDim.x + threadIdx.x;
    if (t >= T) return;
    float wk[2];
#pragma unroll
    for (int s = 0; s < 2; s++) {
        int e = tidx[t * 2 + s];
        float w = tw[t * 2 + s];
        wk[s] = w;
        if (cnt[(s * NE + e) * CSTRIDE] > cap) {   // rare: exact stable-sort rank
            int rank = 0;
            for (int t2 = 0; t2 < T; t2++) {
                if (tidx[t2 * 2 + s] == e) {
                    float w2 = tw[t2 * 2 + s];
                    if (w2 > w || (w2 == w && t2 < t)) rank++;
                }
            }
            if (rank >= cap) wk[s] = 0.f;
        }
    }
    float denom = fmaxf(wk[0] + wk[1], 1e-8f);
    tw2[t * 2]     = wk[0] / denom;
    tw2[t * 2 + 1] = wk[1] / denom;
}

// ---------------- build MERGED per-expert token lists + pos map ----------------
__global__ __launch_bounds__(256) void k_build(const int* __restrict__ tidx,
        const float* __restrict__ tw2, int* __restrict__ lcnt,
        int* __restrict__ ltok, int* __restrict__ pos, int T, int capM)
{
    __shared__ int h[NE];
    __shared__ int base[NE];
    if (threadIdx.x < NE) h[threadIdx.x] = 0;
    __syncthreads();
    int t = blockIdx.x * blockDim.x + threadIdx.x;
    int myE[2] = {-1, -1};
    int myp[2] = {0, 0};
    if (t < T) {
#pragma unroll
        for (int s = 0; s < 2; s++) {
            float w = tw2[t * 2 + s];
            if (w != 0.f) {
                int e = tidx[t * 2 + s];
                myE[s] = e;
                myp[s] = atomicAdd(&h[e], 1);   // LDS atomic
            }
        }
    }
    __syncthreads();
    if (threadIdx.x < NE)
        base[threadIdx.x] = (h[threadIdx.x] != 0)
            ? atomicAdd(&lcnt[threadIdx.x * CSTRIDE], h[threadIdx.x]) : 0;
    __syncthreads();
    if (t < T) {
#pragma unroll
        for (int s = 0; s < 2; s++) {
            if (myE[s] >= 0) {
                int p = base[myE[s]] + myp[s];
                ltok[myE[s] * capM + p] = t;
                pos[t * 2 + s] = (myE[s] << 20) | p;
            } else {
                pos[t * 2 + s] = -1;
            }
        }
    }
}

// ---------------- 128-aligned prefix offsets (merged, 8 experts) ----------------
__global__ void k_off(const int* __restrict__ lcnt, int* __restrict__ loff) {
    if (threadIdx.x == 0 && blockIdx.x == 0) {
        int o = 0;
        for (int e = 0; e < NE; e++) {
            loff[e] = o;
            o += ((lcnt[e * CSTRIDE] + 127) >> 7) << 7;
        }
        loff[NE] = o;
    }
}

// ---------------- fc1: h = gelu(X @ W1^T + b1) ----------------
// Single-buffer 32KB LDS (4 blocks/CU), precomputed swizzled ds_read bases,
// fully-unrolled K so global_load_lds offsets fold to immediates.
__global__ __launch_bounds__(256, 4) void k_fc1(
    const ushort_t* __restrict__ xb, const ushort_t* __restrict__ W1b,
    const float* __restrict__ b1, const int* __restrict__ lcnt,
    const int* __restrict__ loff, const int* __restrict__ ltok,
    ushort_t* __restrict__ hbuf, int capM)
{
    int bx = blockIdx.x;
    int e  = bx & 7;                 // expert == XCD residue
    int r  = bx >> 3;
    int mt = r >> 4;
    int nt = r & 15;
    int cnt = lcnt[e * CSTRIDE];
    if (cnt > capM) cnt = capM;
    int m0 = mt * 128;
    if (m0 >= cnt) return;
    int n0 = nt * 128;
    const int* toks = ltok + e * capM;
    int hrow0 = loff[e] + m0;
    const ushort_t* Bsrc = W1b + (size_t)e * HID * DIM;

    __shared__ char smem[32768];
    char* As = smem;
    char* Bs = smem + 16384;

    int tid = threadIdx.x;
    int wave = tid >> 6, lane = tid & 63;
    int wm = wave >> 1, wn = wave & 1;

    const char* aSrc[4]; const char* bSrc[4]; int ldst[4];
#pragma unroll
    for (int i = 0; i < 4; i++) {
        int c = tid + 256 * i;
        int row = c >> 3, cc = c & 7;
        int scc = cc ^ (row & 7);          // pre-swizzled source column chunk
        int gr = m0 + row;
        int tok = toks[gr < cnt ? gr : (cnt - 1)];
        aSrc[i] = (const char*)(xb + (size_t)tok * DIM + scc * 8);
        bSrc[i] = (const char*)(Bsrc + (size_t)(n0 + row) * DIM + scc * 8);
        ldst[i] = (i * 256 + wave * 64) * 16;
    }

    f32x4 acc[4][4];
#pragma unroll
    for (int a = 0; a < 4; a++)
#pragma unroll
        for (int b = 0; b < 4; b++) acc[a][b] = (f32x4){0.f, 0.f, 0.f, 0.f};

    // precomputed swizzled read bases: rr&7 == lane&7 (wm*64, mf*16 are 0 mod 8)
    int aRow = wm * 64 + (lane & 15);
    int bRow = wn * 64 + (lane & 15);
    int kq = lane >> 4;
    int swz0 = (kq ^ (lane & 7)) << 4;
    int swz1 = ((4 + kq) ^ (lane & 7)) << 4;
    int aoff[2] = { aRow * 128 + swz0, aRow * 128 + swz1 };
    int boff[2] = { bRow * 128 + swz0, bRow * 128 + swz1 };

    auto STAGE = [&](int kofs) {
#pragma unroll
        for (int i = 0; i < 4; i++) {
            gld16(aSrc[i] + kofs, As + ldst[i]);
            gld16(bSrc[i] + kofs, Bs + ldst[i]);
        }
    };
    auto COMPUTE = [&]() {
#pragma unroll
        for (int kk = 0; kk < 2; kk++) {
            short8 af[4], bfr[4];
#pragma unroll
            for (int mf = 0; mf < 4; mf++)
                af[mf] = *(const short8*)(As + aoff[kk] + mf * 2048);
#pragma unroll
            for (int nf = 0; nf < 4; nf++)
                bfr[nf] = *(const short8*)(Bs + boff[kk] + nf * 2048);
#pragma unroll
            for (int mf = 0; mf < 4; mf++)
#pragma unroll
                for (int nf = 0; nf < 4; nf++)
                    acc[mf][nf] = __builtin_amdgcn_mfma_f32_16x16x32_bf16(bfr[nf], af[mf], acc[mf][nf], 0, 0, 0);
        }
    };

#pragma unroll
    for (int kt = 0; kt < DIM / 64; kt++) {   // 8 steps, offsets 0..896 fold to imm
        STAGE(kt * 128);
        __syncthreads();                       // drains vmcnt(0): tile ready
        COMPUTE();
        __syncthreads();                       // protect buffer for next STAGE
    }

    // epilogue: row = wm*64+mf*16+(lane&15); cols = n0+wn*64+nf*16+(lane>>4)*4 + r
    const float* b1e = b1 + e * HID;
    int mlocal = wm * 64 + (lane & 15);
    int nbase0 = n0 + wn * 64 + (lane >> 4) * 4;
#pragma unroll
    for (int mf = 0; mf < 4; mf++) {
        int mrow = mlocal + mf * 16;
        bool valid = (m0 + mrow) < cnt;
        ushort_t* dst = hbuf + (size_t)(hrow0 + mrow) * HID;
#pragma unroll
        for (int nf = 0; nf < 4; nf++) {
            int nc = nbase0 + nf * 16;
            float4 bias4 = *(const float4*)(b1e + nc);
            ushort4 o;
            o.x = f2bf(fast_gelu(acc[mf][nf][0] + bias4.x));
            o.y = f2bf(fast_gelu(acc[mf][nf][1] + bias4.y));
            o.z = f2bf(fast_gelu(acc[mf][nf][2] + bias4.z));
            o.w = f2bf(fast_gelu(acc[mf][nf][3] + bias4.w));
            if (valid) *(ushort4*)(dst + nc) = o;
        }
    }
}

// ---------------- fc2: ybuf[row] = H @ W2^T + b2 (unweighted, bf16) ----------------
__global__ __launch_bounds__(256, 4) void k_fc2(
    const ushort_t* __restrict__ hbuf, const ushort_t* __restrict__ W2b,
    const float* __restrict__ b2, const int* __restrict__ lcnt,
    const int* __restrict__ loff, ushort_t* __restrict__ ybuf, int capM)
{
    int bx = blockIdx.x;
    int e  = bx & 7;
    int r  = bx >> 3;
    int mt = r >> 2;
    int nt = r & 3;
    int cnt = lcnt[e * CSTRIDE];
    if (cnt > capM) cnt = capM;
    int m0 = mt * 128;
    if (m0 >= cnt) return;
    int n0 = nt * 128;
    int hrow0 = loff[e] + m0;
    const ushort_t* Bsrc = W2b + (size_t)e * DIM * HID;

    __shared__ char smem[32768];
    char* As = smem;
    char* Bs = smem + 16384;

    int tid = threadIdx.x;
    int wave = tid >> 6, lane = tid & 63;
    int wm = wave >> 1, wn = wave & 1;

    const char* aSrc[4]; const char* bSrc[4]; int ldst[4];
#pragma unroll
    for (int i = 0; i < 4; i++) {
        int c = tid + 256 * i;
        int row = c >> 3, cc = c & 7;
        int scc = cc ^ (row & 7);
        aSrc[i] = (const char*)(hbuf + (size_t)(hrow0 + row) * HID + scc * 8);
        bSrc[i] = (const char*)(Bsrc + (size_t)(n0 + row) * HID + scc * 8);
        ldst[i] = (i * 256 + wave * 64) * 16;
    }

    f32x4 acc[4][4];
#pragma unroll
    for (int a = 0; a < 4; a++)
#pragma unroll
        for (int b = 0; b < 4; b++) acc[a][b] = (f32x4){0.f, 0.f, 0.f, 0.f};

    int aRow = wm * 64 + (lane & 15);
    int bRow = wn * 64 + (lane & 15);
    int kq = lane >> 4;
    int swz0 = (kq ^ (lane & 7)) << 4;
    int swz1 = ((4 + kq) ^ (lane & 7)) << 4;
    int aoff[2] = { aRow * 128 + swz0, aRow * 128 + swz1 };
    int boff[2] = { bRow * 128 + swz0, bRow * 128 + swz1 };

    auto STAGE = [&](int kofs) {
#pragma unroll
        for (int i = 0; i < 4; i++) {
            gld16(aSrc[i] + kofs, As + ldst[i]);
            gld16(bSrc[i] + kofs, Bs + ldst[i]);
        }
    };
    auto COMPUTE = [&]() {
#pragma unroll
        for (int kk = 0; kk < 2; kk++) {
            short8 af[4], bfr[4];
#pragma unroll
            for (int mf = 0; mf < 4; mf++)
                af[mf] = *(const short8*)(As + aoff[kk] + mf * 2048);
#pragma unroll
            for (int nf = 0; nf < 4; nf++)
                bfr[nf] = *(const short8*)(Bs + boff[kk] + nf * 2048);
#pragma unroll
            for (int mf = 0; mf < 4; mf++)
#pragma unroll
                for (int nf = 0; nf < 4; nf++)
                    acc[mf][nf] = __builtin_amdgcn_mfma_f32_16x16x32_bf16(bfr[nf], af[mf], acc[mf][nf], 0, 0, 0);
        }
    };

    // 32 K-steps: 4 groups of 8 (unrolled, offsets 0..896 imm), bump ptrs 1KB/group
    for (int kg = 0; kg < 4; kg++) {
#pragma unroll
        for (int k8 = 0; k8 < 8; k8++) {
            STAGE(k8 * 128);
            __syncthreads();
            COMPUTE();
            __syncthreads();
        }
#pragma unroll
        for (int i = 0; i < 4; i++) { aSrc[i] += 1024; bSrc[i] += 1024; }
    }

    const float* b2e = b2 + e * DIM;
    int mlocal = wm * 64 + (lane & 15);
    int nbase0 = n0 + wn * 64 + (lane >> 4) * 4;
#pragma unroll
    for (int mf = 0; mf < 4; mf++) {
        int mrow = mlocal + mf * 16;
        bool valid = (m0 + mrow) < cnt;
        ushort_t* dst = ybuf + (size_t)(hrow0 + mrow) * DIM;
#pragma unroll
        for (int nf = 0; nf < 4; nf++) {
            int nc = nbase0 + nf * 16;
            float4 bias4 = *(const float4*)(b2e + nc);
            ushort4 o;
            o.x = f2bf(acc[mf][nf][0] + bias4.x);
            o.y = f2bf(acc[mf][nf][1] + bias4.y);
            o.z = f2bf(acc[mf][nf][2] + bias4.z);
            o.w = f2bf(acc[mf][nf][3] + bias4.w);
            if (valid) *(ushort4*)(dst + nc) = o;
        }
    }
}

// ---------------- combine: out[t] = w0*ybuf[row0] + w1*ybuf[row1] ----------------
__global__ __launch_bounds__(256) void k_comb(const ushort_t* __restrict__ ybuf,
    const float* __restrict__ tw2, const int* __restrict__ pos,
    const int* __restrict__ loff, float* __restrict__ out, int T, int capM)
{
    int wv = threadIdx.x >> 6, lane = threadIdx.x & 63;
    int t = blockIdx.x * 4 + wv;
    if (t >= T) return;
    float o[8];
#pragma unroll
    for (int j = 0; j < 8; j++) o[j] = 0.f;
#pragma unroll
    for (int s = 0; s < 2; s++) {
        int pk = pos[t * 2 + s];
        if (pk >= 0) {
            float w = tw2[t * 2 + s];
            int e = pk >> 20, p = pk & 0xFFFFF;
            int row = loff[e] + p;
            short8 y = *(const short8*)(ybuf + (size_t)row * DIM + lane * 8);
#pragma unroll
            for (int j = 0; j < 8; j++) o[j] += w * bf2f((ushort_t)y[j]);
        }
    }
    float4* dst = (float4*)(out + (size_t)t * DIM + lane * 8);
    dst[0] = (float4){o[0], o[1], o[2], o[3]};
    dst[1] = (float4){o[4], o[5], o[6], o[7]};
}

// ---------------- aux loss: two-stage deterministic reduce ----------------
__global__ __launch_bounds__(256) void k_aux1(const float* __restrict__ probs,
    const float* __restrict__ tw2, const int* __restrict__ tidx,
    float* __restrict__ partial, int T)
{
    __shared__ float red[256 * 16];
    float imp[NE], ld[NE];
#pragma unroll
    for (int e = 0; e < NE; e++) { imp[e] = 0.f; ld[e] = 0.f; }
    int stride = gridDim.x * blockDim.x;
    for (int t = blockIdx.x * blockDim.x + threadIdx.x; t < T; t += stride) {
#pragma unroll
        for (int e = 0; e < NE; e++) imp[e] += probs[(size_t)t * NE + e];
#pragma unroll
        for (int s = 0; s < 2; s++) ld[tidx[t * 2 + s]] += tw2[t * 2 + s];
    }
#pragma unroll
    for (int e = 0; e < NE; e++) {
        red[threadIdx.x * 16 + e] = imp[e];
        red[threadIdx.x * 16 + 8 + e] = ld[e];
    }
    __syncthreads();
    for (int off = 128; off > 0; off >>= 1) {
        if (threadIdx.x < off) {
#pragma unroll
            for (int j = 0; j < 16; j++)
                red[threadIdx.x * 16 + j] += red[(threadIdx.x + off) * 16 + j];
        }
        __syncthreads();
    }
    if (threadIdx.x < 16) partial[blockIdx.x * 16 + threadIdx.x] = red[threadIdx.x];
}

__global__ void k_aux2(const float* __restrict__ partial, float* __restrict__ outaux,
                       int nb, int T)
{
    __shared__ float s[16];
    if (threadIdx.x < 16) {
        float a = 0.f;
        for (int b = 0; b < nb; b++) a += partial[b * 16 + threadIdx.x];
        s[threadIdx.x] = a;
    }
    __syncthreads();
    if (threadIdx.x == 0) {
        float invT = 1.f / (float)T;
        float aux = 0.f;
        for (int e = 0; e < NE; e++)
            aux += (s[e] * invT) * (s[8 + e] * invT) * (float)NE;
        outaux[0] = aux;
    }
}

// ---------------- launch ----------------
extern "C" void kernel_launch(void* const* d_in, const int* in_sizes, int n_in,
                              void* d_out, int out_size, void* d_ws, size_t ws_size,
                              hipStream_t stream)
{
    const float* x  = (const float*)d_in[0];
    const float* Wr = (const float*)d_in[1];
    const float* W1 = (const float*)d_in[2];
    const float* b1 = (const float*)d_in[3];
    const float* W2 = (const float*)d_in[4];
    const float* b2 = (const float*)d_in[5];
    float* out = (float*)d_out;

    int T = in_sizes[0] / DIM;
    int cap = (int)(1.25 * (double)T * 2.0 / 8.0);
    if (cap < 1) cap = 1;
    int capM = 2 * cap; if (capM > T) capM = T;      // merged per-expert bound
    int mtmax = (capM + 127) / 128;

    char* w = (char*)d_ws;
    size_t off = 0;
    auto alloc = [&](size_t bytes) {
        char* p = w + off;
        off = (off + bytes + 255) & ~(size_t)255;
        return p;
    };
    // ybuf overlays xb+W1b (both dead before fc2 writes ybuf)
    size_t ybrows = (size_t)T * 2 + NE * 128;
    size_t ybbytes = ybrows * DIM * 2;
    ushort_t* ybuf = (ushort_t*)w;                    // offset 0
    ushort_t* xb   = (ushort_t*)alloc((size_t)T * DIM * 2);
    ushort_t* W1b  = (ushort_t*)alloc((size_t)NE * HID * DIM * 2);
    if (off < ybbytes) off = (ybbytes + 255) & ~(size_t)255;
    ushort_t* W2b  = (ushort_t*)alloc((size_t)NE * DIM * HID * 2);
    ushort_t* hbuf = (ushort_t*)alloc(ybrows * HID * 2);
    float* probs   = (float*)alloc((size_t)T * NE * 4);
    int*   tidx    = (int*)alloc((size_t)T * 2 * 4);
    float* tw      = (float*)alloc((size_t)T * 2 * 4);
    float* tw2     = (float*)alloc((size_t)T * 2 * 4);
    int*   pos     = (int*)alloc((size_t)T * 2 * 4);
    int*   cnt     = (int*)alloc(16 * CSTRIDE * 4);
    int*   lcnt    = (int*)alloc(NE * CSTRIDE * 4);
    int*   loff    = (int*)alloc((NE + 1) * 4);
    int*   ltok    = (int*)alloc((size_t)NE * capM * 4);
    float* partial = (float*)alloc(64 * 16 * 4);

    (void)hipMemsetAsync(cnt, 0, 16 * CSTRIDE * 4, stream);
    (void)hipMemsetAsync(lcnt, 0, NE * CSTRIDE * 4, stream);

    k_cvt<<<2048, 256, 0, stream>>>(W1, W1b, NE * HID * DIM);
    k_cvt<<<2048, 256, 0, stream>>>(W2, W2b, NE * DIM * HID);
    k_router<<<(T + 3) / 4, 256, 0, stream>>>(x, Wr, xb, probs, tidx, tw, T);
    k_hist<<<64, 256, 0, stream>>>(tidx, cnt, T);
    k_keep<<<(T + 255) / 256, 256, 0, stream>>>(tidx, tw, cnt, tw2, T, cap);
    k_build<<<(T + 255) / 256, 256, 0, stream>>>(tidx, tw2, lcnt, ltok, pos, T, capM);
    k_off<<<1, 64, 0, stream>>>(lcnt, loff);

    k_fc1<<<NE * mtmax * (HID / 128), 256, 0, stream>>>(
        xb, W1b, b1, lcnt, loff, ltok, hbuf, capM);
    k_fc2<<<NE * mtmax * (DIM / 128), 256, 0, stream>>>(
        hbuf, W2b, b2, lcnt, loff, ybuf, capM);
    k_comb<<<(T + 3) / 4, 256, 0, stream>>>(ybuf, tw2, pos, loff, out, T, capM);

    k_aux1<<<64, 256, 0, stream>>>(probs, tw2, tidx, partial, T);
    k_aux2<<<1, 64, 0, stream>>>(partial, out + (size_t)T * DIM, 64, T);
}